// Round 9
// baseline (429.811 us; speedup 1.0000x reference)
//
#include <hip/hip_runtime.h>
#include <cstdint>
#include <cstddef>

typedef __bf16 bf16;
typedef __bf16 bf16x4 __attribute__((ext_vector_type(4)));
typedef __bf16 bf16x8 __attribute__((ext_vector_type(8)));
typedef float  f32x4 __attribute__((ext_vector_type(4)));

#define DEVI __device__ __forceinline__

template <int I> struct ic { static constexpr int value = I; };

// ---------------------------------------------------------------------------
// async global->LDS (16B per lane)
// ---------------------------------------------------------------------------
DEVI void async_ld16(void* lds, const void* g) {
  const __attribute__((address_space(1))) uint32_t* g1 =
      reinterpret_cast<const __attribute__((address_space(1))) uint32_t*>(
          reinterpret_cast<uintptr_t>(g));
  uint32_t lo = (uint32_t)reinterpret_cast<uintptr_t>(lds);
  __attribute__((address_space(3))) uint32_t* l3 =
      reinterpret_cast<__attribute__((address_space(3))) uint32_t*>(lo);
  __builtin_amdgcn_global_load_lds(g1, l3, 16, 0, 0);
}

template <int N> DEVI void wait_vmcnt() {
  asm volatile("s_waitcnt vmcnt(%0)" :: "n"(N) : "memory");
}
DEVI void blk_barrier() {
  asm volatile("" ::: "memory");
  __builtin_amdgcn_s_barrier();
  asm volatile("" ::: "memory");
}
DEVI void wait_lgkm0() {
  asm volatile("s_waitcnt lgkmcnt(0)" ::: "memory");
}

enum { EPI_BF16 = 0, EPI_QKV = 1, EPI_SCORES = 2, EPI_DYT = 3, EPI_GELU = 4, EPI_PRIOR = 5 };

// ---------------------------------------------------------------------------
// 8-phase deep-pipelined B^T GEMM — R8: SINGLE barrier per phase.
// BM=256, BK=64, BN in {256,128}. 8 waves / 512 threads.
// Stage map re-derived so every stage targets a region whose LAST READER is
// >=2 phases earlier (1-barrier/phase skew bound = 1 phase body):
//   readers: buf window = 4 phases; B read at window ph0 (bfr), A quadrant
//   p read at window ph p (half0 by low-wrM waves through ph3, etc).
//   ph0: B(t+1,1)->b1 | ph1: A(t+1,0)->b1 | ph2: A(t+1,1)->b1
//   ph3: B(t+2,0)->b0 +vmcnt(BL2) | ph4: B(t+2,1)->b0
//   ph5: A(t+2,0)->b0 | ph6: A(t+2,1)->b0 | ph7: B(t+3,0)->b1 +vmcnt(BL2)
// vmcnt at ph3 confirms {B(t+1),A(t+1)} (deadline ph4); at ph7 confirms
// {B(t+2),A(t+2)} (deadline next-ph0). Never drains to 0 in main loop.
// No sched_barrier (compiler-visible ds_reads get precise lgkmcnt).
// K-octet XOR swizzle, coalesced LDS-staged epilogue, XCD-chunked swizzle.
// ---------------------------------------------------------------------------
template <int BN, int EPI>
__global__ __launch_bounds__(512, 2) void gemm8(
    const bf16* __restrict__ A, const bf16* __restrict__ Bm, void* __restrict__ Cv,
    int N, int K,
    long long bsA, long long bsB, long long bsC,
    const float* __restrict__ bias, const float* __restrict__ al,
    const float* __restrict__ wv, const float* __restrict__ bv,
    const float* __restrict__ prior, float scale)
{
  constexpr int BM = 256, BK = 64;
  constexpr int MF  = (BN == 256) ? 8 : 4;   // m-frags per wave
  constexpr int MPP = MF / 4;                // m-frags per phase
  constexpr int AELEM = BM * BK;             // 16384
  constexpr int BELEM = BN * BK;
  constexpr int SLOT  = AELEM + BELEM;
  constexpr int BL2   = BN / 128;            // loads per B half-group (2 or 1)

  extern __shared__ __align__(16) bf16 smem[];
  bf16* b0 = smem;
  bf16* b1 = smem + SLOT;

  const int tid = threadIdx.x;

  // XCD-chunked swizzle (all grids are multiples of 8)
  const int gx = gridDim.x, gy = gridDim.y;
  const int nwg = gx * gy * gridDim.z;
  int id = (blockIdx.z * gy + blockIdx.y) * gx + blockIdx.x;
  id = (id & 7) * (nwg >> 3) + (id >> 3);
  const int bx = id % gx;
  const int t1 = id / gx;
  const int by = t1 % gy;
  const int bz = t1 / gy;

  const bf16* Ab = A  + (size_t)bz * bsA + (size_t)by * BM * K;
  const bf16* Bb = Bm + (size_t)bz * bsB + (size_t)bx * BN * K;

  const int lane = tid & 63;
  const int wid  = tid >> 6;
  const int l15  = lane & 15;
  const int lhi  = lane >> 4;
  const int wrM  = (MF == 8) ? (wid >> 2) * 128 : (wid >> 1) * 64;
  const int wcN  = (MF == 8) ? (wid & 3) * 64   : (wid & 1) * 64;

  // staging map: each 8KB load = 64 rows x 64 cols; thread -> (row, octet)
  const int srow  = tid >> 3;                      // 0..63
  const int soct8 = (((tid & 7) ^ (srow & 7)) << 3);  // swizzled src octet
  const int dsto  = tid * 8;                       // lane-linear LDS dst

  // ds_read swizzled octet offsets per k-step
  const int rd0 = (((0 + lhi) ^ (l15 & 7)) << 3);
  const int rd1 = (((4 + lhi) ^ (l15 & 7)) << 3);

  f32x4 acc[MF][4];
  const f32x4 zero = {0.f, 0.f, 0.f, 0.f};
#pragma unroll
  for (int m = 0; m < MF; ++m)
#pragma unroll
    for (int n = 0; n < 4; ++n) acc[m][n] = zero;

  bf16x8 bfr[4][2];  // B fragments, refreshed at phase 0 of each K-tile

  const int NT = K / BK;   // 16/32/64 (even, >=16)
  const int NI = NT / 2;

  auto SA = [&](int t, int half, bf16* buf) {   // stage A half (2 loads)
    const size_t kb = (size_t)t * BK;
#pragma unroll
    for (int j = 0; j < 2; ++j) {
      const int rl = half * 128 + j * 64 + srow;
      async_ld16(buf + half * 8192 + j * 4096 + dsto,
                 Ab + (size_t)rl * K + kb + soct8);
    }
  };
  auto SB = [&](int t, int half, bf16* buf) {   // stage B half (BL2 loads)
    const size_t kb = (size_t)t * BK;
#pragma unroll
    for (int j = 0; j < BL2; ++j) {
      const int rl = half * (BN / 2) + j * 64 + srow;
      async_ld16(buf + AELEM + half * (BELEM / 2) + j * 4096 + dsto,
                 Bb + (size_t)rl * K + kb + soct8);
    }
  };

  // one phase: p = 0..3 (compile-time), vmc: -1 none / 0 / BL2
  auto phase = [&](auto pc, const bf16* buf, auto&& stage, auto vmc) {
    constexpr int p  = decltype(pc)::value;
    constexpr int vm = decltype(vmc)::value;
    if constexpr (p == 0) {
#pragma unroll
      for (int n = 0; n < 4; ++n) {
        const int row = wcN + n * 16 + l15;
        bfr[n][0] = *(const bf16x8*)&buf[AELEM + row * BK + rd0];
        bfr[n][1] = *(const bf16x8*)&buf[AELEM + row * BK + rd1];
      }
    }
    bf16x8 af[MPP][2];
#pragma unroll
    for (int mm = 0; mm < MPP; ++mm) {
      const int row = wrM + (p * MPP + mm) * 16 + l15;
      af[mm][0] = *(const bf16x8*)&buf[row * BK + rd0];
      af[mm][1] = *(const bf16x8*)&buf[row * BK + rd1];
    }
    stage();
    if constexpr (vm >= 0) wait_vmcnt<vm>();
    blk_barrier();
    wait_lgkm0();
    __builtin_amdgcn_s_setprio(1);
#pragma unroll
    for (int mm = 0; mm < MPP; ++mm)
#pragma unroll
      for (int ks = 0; ks < 2; ++ks)
#pragma unroll
        for (int n = 0; n < 4; ++n)
          acc[p * MPP + mm][n] =
              __builtin_amdgcn_mfma_f32_16x16x32_bf16(af[mm][ks], bfr[n][ks],
                                                      acc[p * MPP + mm][n], 0, 0, 0);
    __builtin_amdgcn_s_setprio(0);
    // no trailing barrier (stage map guarantees >=2-phase reader/writer gaps)
  };

  auto NOP = [&] {};

  // prologue: tile0 fully into b0 + tile1's B0 into b1; leave B0 in flight
  SB(0, 0, b0); SB(0, 1, b0); SA(0, 0, b0); SA(0, 1, b0);
  SB(1, 0, b1);
  wait_vmcnt<BL2>();
  blk_barrier();

  for (int i = 0; i < NI - 1; ++i) {
    const int t = 2 * i;
    phase(ic<0>{}, b0, [&] { SB(t + 1, 1, b1); }, ic<-1>{});
    phase(ic<1>{}, b0, [&] { SA(t + 1, 0, b1); }, ic<-1>{});
    phase(ic<2>{}, b0, [&] { SA(t + 1, 1, b1); }, ic<-1>{});
    phase(ic<3>{}, b0, [&] { SB(t + 2, 0, b0); }, ic<BL2>{});
    phase(ic<0>{}, b1, [&] { SB(t + 2, 1, b0); }, ic<-1>{});
    phase(ic<1>{}, b1, [&] { SA(t + 2, 0, b0); }, ic<-1>{});
    phase(ic<2>{}, b1, [&] { SA(t + 2, 1, b0); }, ic<-1>{});
    phase(ic<3>{}, b1, [&] { SB(t + 3, 0, b1); }, ic<BL2>{});
  }
  {  // final iteration (t = NT-2): finish staging tile NT-1, then drain
    const int t = NT - 2;
    phase(ic<0>{}, b0, [&] { SB(t + 1, 1, b1); }, ic<-1>{});
    phase(ic<1>{}, b0, [&] { SA(t + 1, 0, b1); }, ic<-1>{});
    phase(ic<2>{}, b0, [&] { SA(t + 1, 1, b1); }, ic<-1>{});
    phase(ic<3>{}, b0, NOP, ic<0>{});
    phase(ic<0>{}, b1, NOP, ic<-1>{});
    phase(ic<1>{}, b1, NOP, ic<-1>{});
    phase(ic<2>{}, b1, NOP, ic<-1>{});
    phase(ic<3>{}, b1, NOP, ic<-1>{});
  }

  // ---------------- epilogue: LDS-staged, coalesced ----------------
  __syncthreads();

  const int ccol_base = bx * BN + wcN;
  const int wrow0 = by * BM + wrM;

  float a2v = 0.f;
  if constexpr (EPI == EPI_DYT) a2v = al[0];

  constexpr bool F32OUT = (EPI == EPI_SCORES || EPI == EPI_PRIOR);

  if constexpr (F32OUT) {
    float* st = (float*)smem + wid * (32 * 68);
    const int lane4r = lane >> 4, lane16c = lane & 15;
    const int gcol = ccol_base + lane16c * 4;
#pragma unroll
    for (int mp = 0; mp < MF / 2; ++mp) {
#pragma unroll
      for (int mm = 0; mm < 2; ++mm) {
        const int m = mp * 2 + mm;
#pragma unroll
        for (int n = 0; n < 4; ++n) {
          const int col = ccol_base + n * 16 + l15;
          float bcol = 0.f;
          if constexpr (EPI == EPI_PRIOR) bcol = bias[col];
#pragma unroll
          for (int r = 0; r < 4; ++r) {
            const int lr = mm * 16 + (lhi << 2) + r;
            float v = acc[m][n][r];
            if constexpr (EPI == EPI_SCORES) {
              const int row = wrow0 + mp * 32 + lr;
              v = v * scale - fabsf((float)(row - col));
            } else {
              v += bcol;
            }
            st[lr * 68 + n * 16 + l15] = v;
          }
        }
      }
      wait_lgkm0();
#pragma unroll
      for (int k = 0; k < 8; ++k) {
        const int lr = lane4r + 4 * k;
        f32x4 v = *(const f32x4*)&st[lr * 68 + lane16c * 4];
        const int grow = wrow0 + mp * 32 + lr;
        float* C = (float*)Cv + (size_t)bz * bsC;
        if constexpr (EPI == EPI_PRIOR) {
          const float4 p = *(const float4*)&prior[(size_t)grow * 1024 + gcol];
          v[0] += p.x; v[1] += p.y; v[2] += p.z; v[3] += p.w;
        }
        *(f32x4*)&C[(size_t)grow * N + gcol] = v;
      }
      wait_lgkm0();
    }
  } else {
    bf16* st = (bf16*)smem + wid * (32 * 72);
    const int lane8r = lane >> 3, lane8c = lane & 7;
#pragma unroll
    for (int mp = 0; mp < MF / 2; ++mp) {
#pragma unroll
      for (int mm = 0; mm < 2; ++mm) {
        const int m = mp * 2 + mm;
#pragma unroll
        for (int n = 0; n < 4; ++n) {
          const int col = ccol_base + n * 16 + l15;
          float bcol = 0.f, wcol = 0.f, bvcol = 0.f;
          if constexpr (EPI == EPI_DYT) { bcol = bias[col]; wcol = wv[col]; bvcol = bv[col]; }
          if constexpr (EPI == EPI_GELU) bcol = bias[col];
#pragma unroll
          for (int r = 0; r < 4; ++r) {
            const int lr = mm * 16 + (lhi << 2) + r;
            const float v = acc[m][n][r];
            bf16 o;
            if constexpr (EPI == EPI_DYT) {
              o = (bf16)(tanhf(a2v * (v + bcol)) * wcol + bvcol);
            } else if constexpr (EPI == EPI_GELU) {
              const float g = v + bcol;
              o = (bf16)(0.5f * g * (1.0f + erff(g * 0.70710678118654752f)));
            } else {
              o = (bf16)v;
            }
            st[lr * 72 + n * 16 + l15] = o;
          }
        }
      }
      wait_lgkm0();
#pragma unroll
      for (int k = 0; k < 4; ++k) {
        const int lr = lane8r + 8 * k;
        const bf16x8 v = *(const bf16x8*)&st[lr * 72 + lane8c * 8];
        const int grow = wrow0 + mp * 32 + lr;
        if constexpr (EPI == EPI_QKV) {
          bf16* C = (bf16*)Cv + (size_t)(ccol_base >> 10) * bsC;
          *(bf16x8*)&C[(size_t)grow * 1024 + (ccol_base & 1023) + lane8c * 8] = v;
        } else {
          bf16* C = (bf16*)Cv + (size_t)bz * bsC;
          *(bf16x8*)&C[(size_t)grow * N + ccol_base + lane8c * 8] = v;
        }
      }
      wait_lgkm0();
    }
  }
}

// ---------------------------------------------------------------------------
// fused: xpe = x + pos_embed; prior = dyt3(xpe) (fp32); xn = dyt1(xpe) (bf16)
// ---------------------------------------------------------------------------
__global__ __launch_bounds__(256) void ew_pre(
    const float* __restrict__ x, const float* __restrict__ pe,
    const float* __restrict__ a1p, const float* __restrict__ w1, const float* __restrict__ b1,
    const float* __restrict__ a3p, const float* __restrict__ w3, const float* __restrict__ b3,
    float* __restrict__ prior, bf16* __restrict__ xn, int total4)
{
  const float a1 = a1p[0], a3 = a3p[0];
  for (int i = blockIdx.x * 256 + threadIdx.x; i < total4; i += gridDim.x * 256) {
    const int dq = i & 255;
    const float4 xv  = ((const float4*)x)[i];
    const float4 pv  = ((const float4*)pe)[dq];
    const float4 w1v = ((const float4*)w1)[dq];
    const float4 b1v = ((const float4*)b1)[dq];
    const float4 w3v = ((const float4*)w3)[dq];
    const float4 b3v = ((const float4*)b3)[dq];
    const float x0 = xv.x + pv.x, x1 = xv.y + pv.y, x2 = xv.z + pv.z, x3 = xv.w + pv.w;
    float4 prv;
    prv.x = tanhf(a3 * x0) * w3v.x + b3v.x;
    prv.y = tanhf(a3 * x1) * w3v.y + b3v.y;
    prv.z = tanhf(a3 * x2) * w3v.z + b3v.z;
    prv.w = tanhf(a3 * x3) * w3v.w + b3v.w;
    ((float4*)prior)[i] = prv;
    bf16x4 o;
    o[0] = (bf16)(tanhf(a1 * x0) * w1v.x + b1v.x);
    o[1] = (bf16)(tanhf(a1 * x1) * w1v.y + b1v.y);
    o[2] = (bf16)(tanhf(a1 * x2) * w1v.z + b1v.z);
    o[3] = (bf16)(tanhf(a1 * x3) * w1v.w + b1v.w);
    ((bf16x4*)xn)[i] = o;
  }
}

// fp32 -> bf16 weight conversion, 6 segments via blockIdx.y
__global__ __launch_bounds__(256) void conv_w(
    const float* __restrict__ s0, const float* __restrict__ s1, const float* __restrict__ s2,
    const float* __restrict__ s3, const float* __restrict__ s4, const float* __restrict__ s5,
    bf16* __restrict__ d0, bf16* __restrict__ d1, bf16* __restrict__ d2,
    bf16* __restrict__ d3, bf16* __restrict__ d4, bf16* __restrict__ d5,
    int n0, int n1, int n2, int n3, int n4, int n5)
{
  const float* s; bf16* d; int n;
  switch (blockIdx.y) {
    case 0: s = s0; d = d0; n = n0; break;
    case 1: s = s1; d = d1; n = n1; break;
    case 2: s = s2; d = d2; n = n2; break;
    case 3: s = s3; d = d3; n = n3; break;
    case 4: s = s4; d = d4; n = n4; break;
    default: s = s5; d = d5; n = n5; break;
  }
  const int nq = n >> 2;
  for (int i = blockIdx.x * 256 + threadIdx.x; i < nq; i += gridDim.x * 256) {
    const float4 v = ((const float4*)s)[i];
    bf16x4 o;
    o[0] = (bf16)v.x; o[1] = (bf16)v.y; o[2] = (bf16)v.z; o[3] = (bf16)v.w;
    ((bf16x4*)d)[i] = o;
  }
}

// V [B][T][D] -> Vt [B][D][T]
__global__ __launch_bounds__(256) void transpose_k(const bf16* __restrict__ in, bf16* __restrict__ out) {
  __shared__ bf16 tile[64][65];
  const int bx = blockIdx.x;
  const int by = blockIdx.y;
  const int bz = blockIdx.z;
  const bf16* ib = in  + (size_t)bz * 2048 * 1024;
  bf16* ob       = out + (size_t)bz * 1024 * 2048;
  const int tx = threadIdx.x & 15, ty = threadIdx.x >> 4;
#pragma unroll
  for (int i = 0; i < 4; ++i) {
    const int r = ty + i * 16;
    const bf16x4 v = *(const bf16x4*)(ib + (size_t)(by * 64 + r) * 1024 + bx * 64 + tx * 4);
    tile[r][tx * 4 + 0] = v[0]; tile[r][tx * 4 + 1] = v[1];
    tile[r][tx * 4 + 2] = v[2]; tile[r][tx * 4 + 3] = v[3];
  }
  __syncthreads();
#pragma unroll
  for (int i = 0; i < 4; ++i) {
    const int r = ty + i * 16;
    const int c = tx * 4;
    bf16x4 v;
    v[0] = tile[c + 0][r]; v[1] = tile[c + 1][r];
    v[2] = tile[c + 2][r]; v[3] = tile[c + 3][r];
    *(bf16x4*)(ob + (size_t)(bx * 64 + r) * 2048 + by * 64 + c) = v;
  }
}

// ---------------------------------------------------------------------------
// reductions
// ---------------------------------------------------------------------------
DEVI float wave_red_max(float v) {
#pragma unroll
  for (int o = 32; o > 0; o >>= 1) v = fmaxf(v, __shfl_xor(v, o));
  return v;
}
DEVI float wave_red_sum(float v) {
#pragma unroll
  for (int o = 32; o > 0; o >>= 1) v += __shfl_xor(v, o);
  return v;
}
DEVI float block_red_max(float v, float* sm) {
  v = wave_red_max(v);
  if ((threadIdx.x & 63) == 0) sm[threadIdx.x >> 6] = v;
  __syncthreads();
  v = fmaxf(fmaxf(sm[0], sm[1]), fmaxf(sm[2], sm[3]));
  __syncthreads();
  return v;
}
DEVI float block_red_sum(float v, float* sm) {
  v = wave_red_sum(v);
  if ((threadIdx.x & 63) == 0) sm[threadIdx.x >> 6] = v;
  __syncthreads();
  v = sm[0] + sm[1] + sm[2] + sm[3];
  __syncthreads();
  return v;
}

// row softmax over 2048 scores (fp32 in) -> bf16 probs
__global__ __launch_bounds__(256) void softmax_k(const float* __restrict__ scores, bf16* __restrict__ probs) {
  __shared__ float sm[4];
  const size_t row = blockIdx.x;
  const float* s = scores + row * 2048;
  bf16* p = probs + row * 2048;
  const int t = threadIdx.x;
  const float4 v0 = *(const float4*)&s[t * 4];
  const float4 v1 = *(const float4*)&s[1024 + t * 4];
  float mx = fmaxf(fmaxf(fmaxf(v0.x, v0.y), fmaxf(v0.z, v0.w)),
                   fmaxf(fmaxf(v1.x, v1.y), fmaxf(v1.z, v1.w)));
  mx = block_red_max(mx, sm);
  const float e0 = expf(v0.x - mx), e1 = expf(v0.y - mx), e2 = expf(v0.z - mx), e3 = expf(v0.w - mx);
  const float e4 = expf(v1.x - mx), e5 = expf(v1.y - mx), e6 = expf(v1.z - mx), e7 = expf(v1.w - mx);
  float ssum = e0 + e1 + e2 + e3 + e4 + e5 + e6 + e7;
  ssum = block_red_sum(ssum, sm);
  const float inv = 1.0f / ssum;
  bf16x4 o0, o1;
  o0[0] = (bf16)(e0 * inv); o0[1] = (bf16)(e1 * inv); o0[2] = (bf16)(e2 * inv); o0[3] = (bf16)(e3 * inv);
  o1[0] = (bf16)(e4 * inv); o1[1] = (bf16)(e5 * inv); o1[2] = (bf16)(e6 * inv); o1[3] = (bf16)(e7 * inv);
  *(bf16x4*)&p[t * 4] = o0;
  *(bf16x4*)&p[1024 + t * 4] = o1;
}

// per-row JS pieces -> per-row partials
__global__ __launch_bounds__(256) void loss_k(const float* __restrict__ prior,
                                              const float* __restrict__ post,
                                              float* __restrict__ partial) {
  __shared__ float sm[4];
  const size_t row = blockIdx.x;
  const int t = threadIdx.x;
  const float4 pr = *(const float4*)&prior[row * 1024 + t * 4];
  const float4 po = *(const float4*)&post[row * 1024 + t * 4];
  float4 mm;
  mm.x = 0.5f * (pr.x + po.x); mm.y = 0.5f * (pr.y + po.y);
  mm.z = 0.5f * (pr.z + po.z); mm.w = 0.5f * (pr.w + po.w);
  const float mxp = block_red_max(fmaxf(fmaxf(pr.x, pr.y), fmaxf(pr.z, pr.w)), sm);
  const float mxo = block_red_max(fmaxf(fmaxf(po.x, po.y), fmaxf(po.z, po.w)), sm);
  const float mxm = block_red_max(fmaxf(fmaxf(mm.x, mm.y), fmaxf(mm.z, mm.w)), sm);
  float sp = expf(pr.x - mxp) + expf(pr.y - mxp) + expf(pr.z - mxp) + expf(pr.w - mxp);
  sp = block_red_sum(sp, sm);
  float so = expf(po.x - mxo) + expf(po.y - mxo) + expf(po.z - mxo) + expf(po.w - mxo);
  so = block_red_sum(so, sm);
  const float em0 = expf(mm.x - mxm), em1 = expf(mm.y - mxm), em2 = expf(mm.z - mxm), em3 = expf(mm.w - mxm);
  float smm = block_red_sum(em0 + em1 + em2 + em3, sm);
  const float invm = 1.0f / smm;
  float s1 = em0 * invm * (mm.x - pr.x) + em1 * invm * (mm.y - pr.y) +
             em2 * invm * (mm.z - pr.z) + em3 * invm * (mm.w - pr.w);
  float s2 = em0 * invm * (mm.x - po.x) + em1 * invm * (mm.y - po.y) +
             em2 * invm * (mm.z - po.z) + em3 * invm * (mm.w - po.w);
  s1 = block_red_sum(s1, sm);
  s2 = block_red_sum(s2, sm);
  if (t == 0) {
    const float logZp = mxp + logf(sp);
    const float logZo = mxo + logf(so);
    const float logZm = mxm + logf(smm);
    partial[row]        = s1 + (logZp - logZm);
    partial[8192 + row] = s2 + (logZo - logZm);
  }
}

__global__ __launch_bounds__(1024) void loss_fin(const float* __restrict__ partial,
                                                 float* __restrict__ out) {
  __shared__ float sm[32];
  const int t = threadIdx.x;
  float a = 0.f, b = 0.f;
  for (int i = t; i < 8192; i += 1024) {
    a += partial[i];
    b += partial[8192 + i];
  }
  float v = a + b;
#pragma unroll
  for (int o = 32; o > 0; o >>= 1) v += __shfl_xor(v, o);
  if ((t & 63) == 0) sm[t >> 6] = v;
  __syncthreads();
  if (t == 0) {
    float s = 0.f;
#pragma unroll
    for (int w = 0; w < 16; ++w) s += sm[w];
    out[0] = 0.125f * s;
  }
}

// ---------------------------------------------------------------------------
extern "C" void kernel_launch(void* const* d_in, const int* in_sizes, int n_in,
                              void* d_out, int out_size, void* d_ws, size_t ws_size,
                              hipStream_t stream) {
  const float* x  = (const float*)d_in[0];
  const float* pe = (const float*)d_in[1];
  const float* a1 = (const float*)d_in[2];
  const float* w1 = (const float*)d_in[3];
  const float* b1 = (const float*)d_in[4];
  const float* a2 = (const float*)d_in[5];
  const float* w2 = (const float*)d_in[6];
  const float* b2 = (const float*)d_in[7];
  const float* a3 = (const float*)d_in[8];
  const float* w3 = (const float*)d_in[9];
  const float* b3 = (const float*)d_in[10];
  const float* Wq = (const float*)d_in[11];
  const float* Wk = (const float*)d_in[12];
  const float* Wv = (const float*)d_in[13];
  const float* Wp = (const float*)d_in[14];
  const float* bp = (const float*)d_in[15];
  const float* We = (const float*)d_in[16];
  const float* be = (const float*)d_in[17];
  const float* Wc = (const float*)d_in[18];
  const float* bc = (const float*)d_in[19];
  float* out = (float*)d_out;

  char* ws = (char*)d_ws;
  float* prior  = (float*)(ws + 0);
  bf16*  xn     = (bf16*)(ws + 33554432ull);
  bf16*  Qb     = (bf16*)(ws + 50331648ull);
  bf16*  Kb     = (bf16*)(ws + 67108864ull);
  bf16*  Vb     = (bf16*)(ws + 83886080ull);
  bf16*  Vt     = (bf16*)(ws + 100663296ull);
  float* scores = (float*)(ws + 117440512ull);
  bf16*  Wqb    = (bf16*)(ws + 184549376ull);   // Wq/Wk/Wv contiguous
  bf16*  Wkb    = (bf16*)(ws + 186646528ull);
  bf16*  Wvb    = (bf16*)(ws + 188743680ull);
  bf16*  Wpb    = (bf16*)(ws + 190840832ull);
  bf16*  Web    = (bf16*)(ws + 192937984ull);
  bf16*  Wcb    = (bf16*)(ws + 201326592ull);
  bf16*  attno  = xn;
  bf16*  h2     = Qb;
  bf16*  eb     = (bf16*)scores;
  float* partial = (float*)(ws + 117440512ull);
  bf16*  probs  = (bf16*)d_out;

  static bool attr_done = false;
  if (!attr_done) {
    hipFuncSetAttribute((const void*)gemm8<256, EPI_QKV>,   hipFuncAttributeMaxDynamicSharedMemorySize, 131072);
    hipFuncSetAttribute((const void*)gemm8<256, EPI_SCORES>,hipFuncAttributeMaxDynamicSharedMemorySize, 131072);
    hipFuncSetAttribute((const void*)gemm8<256, EPI_GELU>,  hipFuncAttributeMaxDynamicSharedMemorySize, 131072);
    hipFuncSetAttribute((const void*)gemm8<128, EPI_BF16>,  hipFuncAttributeMaxDynamicSharedMemorySize, 98304);
    hipFuncSetAttribute((const void*)gemm8<128, EPI_DYT>,   hipFuncAttributeMaxDynamicSharedMemorySize, 98304);
    hipFuncSetAttribute((const void*)gemm8<128, EPI_PRIOR>, hipFuncAttributeMaxDynamicSharedMemorySize, 98304);
    attr_done = true;
  }

  dim3 blk(256);
  dim3 gblk(512);
  constexpr unsigned SHA = 131072;   // BN=256: 2 x 64KB
  constexpr unsigned SHB = 98304;    // BN=128: 2 x 48KB

  conv_w<<<dim3(1024, 6), blk, 0, stream>>>(Wq, Wk, Wv, Wp, We, Wc,
                                            Wqb, Wkb, Wvb, Wpb, Web, Wcb,
                                            1048576, 1048576, 1048576, 1048576, 4194304, 4194304);
  ew_pre<<<2048, blk, 0, stream>>>(x, pe, a1, w1, b1, a3, w3, b3, prior, xn, 2097152);

  // fused QKV: [8192,3072] = xn @ [Wq;Wk;Wv]^T   (384 blocks)
  gemm8<256, EPI_QKV><<<dim3(12, 32, 1), gblk, SHA, stream>>>(xn, Wqb, Qb, 3072, 1024,
      0, 0, 8388608ll, nullptr, nullptr, nullptr, nullptr, nullptr, 0.f);
  transpose_k<<<dim3(16, 32, 4), blk, 0, stream>>>(Vb, Vt);

  // scores[b,t,s] = (Q·K)/32 - |t-s|   (256 blocks)
  gemm8<256, EPI_SCORES><<<dim3(8, 8, 4), gblk, SHA, stream>>>(Qb, Kb, scores, 2048, 1024,
      2097152ll, 2097152ll, 4194304ll, nullptr, nullptr, nullptr, nullptr, nullptr, 0.03125f);
  softmax_k<<<8192, blk, 0, stream>>>(scores, probs);

  // out[b,t,d] = probs @ Vt   (256 blocks)
  gemm8<128, EPI_BF16><<<dim3(8, 8, 4), gblk, SHB, stream>>>(probs, Vt, attno, 1024, 2048,
      4194304ll, 2097152ll, 2097152ll, nullptr, nullptr, nullptr, nullptr, nullptr, 0.f);

  // proj + dyt2   (256 blocks)
  gemm8<128, EPI_DYT><<<dim3(8, 32, 1), gblk, SHB, stream>>>(attno, Wpb, h2, 1024, 1024,
      0, 0, 0, bp, a2, w2, b2, nullptr, 0.f);
  // expand + exact gelu   (512 blocks)
  gemm8<256, EPI_GELU><<<dim3(16, 32, 1), gblk, SHA, stream>>>(h2, Web, eb, 4096, 1024,
      0, 0, 0, be, nullptr, nullptr, nullptr, nullptr, 0.f);
  // contract + bias + prior -> posterior   (256 blocks)
  gemm8<128, EPI_PRIOR><<<dim3(8, 32, 1), gblk, SHB, stream>>>(eb, Wcb, out, 1024, 4096,
      0, 0, 0, bc, nullptr, nullptr, nullptr, prior, 0.f);

  loss_k<<<8192, blk, 0, stream>>>(prior, out, partial);
  loss_fin<<<1, 1024, 0, stream>>>(partial, out + 8388608);
}

// Round 11
// 414.205 us; speedup vs baseline: 1.0377x; 1.0377x over previous
//
#include <hip/hip_runtime.h>
#include <cstdint>
#include <cstddef>

typedef __bf16 bf16;
typedef __bf16 bf16x4 __attribute__((ext_vector_type(4)));
typedef __bf16 bf16x8 __attribute__((ext_vector_type(8)));
typedef float  f32x4 __attribute__((ext_vector_type(4)));

#define DEVI __device__ __forceinline__

// ---------------------------------------------------------------------------
// async global->LDS (16B per lane)
// ---------------------------------------------------------------------------
DEVI void async_ld16(void* lds, const void* g) {
  const __attribute__((address_space(1))) uint32_t* g1 =
      reinterpret_cast<const __attribute__((address_space(1))) uint32_t*>(
          reinterpret_cast<uintptr_t>(g));
  uint32_t lo = (uint32_t)reinterpret_cast<uintptr_t>(lds);
  __attribute__((address_space(3))) uint32_t* l3 =
      reinterpret_cast<__attribute__((address_space(3))) uint32_t*>(lo);
  __builtin_amdgcn_global_load_lds(g1, l3, 16, 0, 0);
}

template <int N> DEVI void wait_vmcnt() {
  asm volatile("s_waitcnt vmcnt(%0)" :: "n"(N) : "memory");
}
DEVI void blk_barrier() {
  asm volatile("" ::: "memory");
  __builtin_amdgcn_s_barrier();
  asm volatile("" ::: "memory");
}
DEVI void wait_lgkm0() {
  asm volatile("s_waitcnt lgkmcnt(0)" ::: "memory");
}

enum { EPI_BF16 = 0, EPI_QKV = 1, EPI_SCORES = 2, EPI_DYT = 3, EPI_GELU = 4, EPI_PRIOR = 5 };

// ---------------------------------------------------------------------------
// B^T GEMM: C[row,col] = sum_k A[row,k]*B[col,k]   (R5 structure = best
// measured: 416.6us config). BM=128, BN=256, BK=32, 8 waves (512 thr, 2Mx4N),
// ring-3 LDS (72KB) + __launch_bounds__(512,4) -> 2 blocks/CU. Counted vmcnt
// (never 0 in main loop), raw s_barrier x2 per K-tile, setprio on MFMA.
// K-octet XOR swizzle both sides. Coalesced LDS-staged epilogue.
// R10 NEW: EPI_QKV writes the V third TRANSPOSED (Vt[b][d][t]) straight from
// the epilogue LDS stage -> transpose_k kernel + Vb round-trip eliminated.
// Vt lives at (bf16*)Cv + 2*bsC so no extra kernel argument is needed.
// ---------------------------------------------------------------------------
template <int EPI>
__global__ __launch_bounds__(512, 4) void gemm2(
    const bf16* __restrict__ A, const bf16* __restrict__ Bm, void* __restrict__ Cv,
    int N, int K,
    long long bsA, long long bsB, long long bsC,
    const float* __restrict__ bias, const float* __restrict__ al,
    const float* __restrict__ wv, const float* __restrict__ bv,
    const float* __restrict__ prior, float scale)
{
  constexpr int BM = 128;
  constexpr int BN = 256;
  constexpr int BK = 32;
  constexpr int ASZ = BM * BK;          // 4096 elems
  constexpr int SLOT = ASZ + BN * BK;   // 12288 elems = 24KB
  constexpr int L = 3;                  // loads per thread per tile (1 A + 2 B)
  constexpr int MF = 4;                 // m-frags per wave (128/2/16)

  extern __shared__ __align__(16) bf16 smem[];  // 3 * SLOT

  const int tid = threadIdx.x;

  // T1 XCD-chunked swizzle (nwg always a multiple of 8)
  const int gx = gridDim.x, gy = gridDim.y;
  const int nwg = gx * gy * gridDim.z;
  int id = (blockIdx.z * gy + blockIdx.y) * gx + blockIdx.x;
  id = (id & 7) * (nwg >> 3) + (id >> 3);
  const int bx = id % gx;
  const int t1 = id / gx;
  const int by = t1 % gy;
  const int bz = t1 / gy;

  const bf16* Ab = A  + (size_t)bz * bsA + (size_t)by * BM * K;
  const bf16* Bb = Bm + (size_t)bz * bsB + (size_t)bx * BN * K;

  const int lane = tid & 63;
  const int wid  = tid >> 6;
  const int l15 = lane & 15;
  const int lhi = lane >> 4;
  const int wr = (wid >> 2) * 64;
  const int wc = (wid & 3) * 64;

  // staging: thread -> (row = tid>>2, slot p = tid&3); LDS dst linear in lane.
  // source k-octet = p ^ ((row>>1)&3)  (inverse swizzle on global address)
  const int srow = tid >> 2;
  const int sp   = tid & 3;
  const int soct = (sp ^ ((srow >> 1) & 3)) << 3;
  const bf16* aSrc  = Ab + (size_t)srow * K + soct;
  const bf16* bSrc0 = Bb + (size_t)srow * K + soct;
  const bf16* bSrc1 = Bb + (size_t)(srow + 128) * K + soct;
  const int dstA = tid * 8;             // elems within slot
  const int dstB0 = ASZ + tid * 8;
  const int dstB1 = ASZ + 4096 + tid * 8;

  // ds_read swizzled k-offset: lhi ^ ((l15>>1)&3)  (independent of m,n)
  const int koff = ((lhi ^ ((l15 >> 1) & 3)) << 3);

  f32x4 acc[MF][4];
  const f32x4 zero = {0.f, 0.f, 0.f, 0.f};
#pragma unroll
  for (int m = 0; m < MF; ++m)
#pragma unroll
    for (int n = 0; n < 4; ++n) acc[m][n] = zero;

  const int NT = K / BK;

  auto STAGE = [&](int t) {
    bf16* dst = smem + (size_t)(t % 3) * SLOT;
    const size_t kb = (size_t)t * BK;
    async_ld16(dst + dstA,  aSrc  + kb);
    async_ld16(dst + dstB0, bSrc0 + kb);
    async_ld16(dst + dstB1, bSrc1 + kb);
  };

  auto COMPUTE = [&](int t) {
    const bf16* buf = smem + (size_t)(t % 3) * SLOT;
    bf16x8 bf_[4];
#pragma unroll
    for (int n = 0; n < 4; ++n)
      bf_[n] = *(const bf16x8*)&buf[ASZ + (wc + n * 16 + l15) * BK + koff];
    __builtin_amdgcn_s_setprio(1);
#pragma unroll
    for (int m = 0; m < MF; ++m) {
      const bf16x8 af_ = *(const bf16x8*)&buf[(wr + m * 16 + l15) * BK + koff];
#pragma unroll
      for (int n = 0; n < 4; ++n)
        acc[m][n] = __builtin_amdgcn_mfma_f32_16x16x32_bf16(af_, bf_[n], acc[m][n], 0, 0, 0);
    }
    __builtin_amdgcn_s_setprio(0);
  };

  STAGE(0); STAGE(1);

  for (int t = 0; t < NT - 2; ++t) {
    STAGE(t + 2);
    wait_vmcnt<2 * L>();
    blk_barrier();
    COMPUTE(t);
    blk_barrier();
  }
  wait_vmcnt<L>(); blk_barrier(); COMPUTE(NT - 2); blk_barrier();
  wait_vmcnt<0>(); blk_barrier(); COMPUTE(NT - 1);

  // ---------------- epilogue: LDS-staged, coalesced ----------------
  __syncthreads();

  const int ccol_base = bx * BN + wc;
  const int wrow0 = by * BM + wr;

  float a2v = 0.f;
  if constexpr (EPI == EPI_DYT) a2v = al[0];

  constexpr bool F32OUT = (EPI == EPI_SCORES || EPI == EPI_PRIOR);

  if constexpr (F32OUT) {
    float* st = (float*)smem + wid * (32 * 68);
    const int lane4r = lane >> 4, lane16c = lane & 15;
    const int gcol = ccol_base + lane16c * 4;
#pragma unroll
    for (int mp = 0; mp < MF / 2; ++mp) {
#pragma unroll
      for (int mm = 0; mm < 2; ++mm) {
        const int m = mp * 2 + mm;
#pragma unroll
        for (int n = 0; n < 4; ++n) {
          const int col = ccol_base + n * 16 + l15;
          float bcol = 0.f;
          if constexpr (EPI == EPI_PRIOR) bcol = bias[col];
#pragma unroll
          for (int r = 0; r < 4; ++r) {
            const int lr = mm * 16 + (lhi << 2) + r;
            float v = acc[m][n][r];
            if constexpr (EPI == EPI_SCORES) {
              const int row = wrow0 + mp * 32 + lr;
              v = v * scale - fabsf((float)(row - col));
            } else {
              v += bcol;
            }
            st[lr * 68 + n * 16 + l15] = v;
          }
        }
      }
      wait_lgkm0();
#pragma unroll
      for (int k = 0; k < 8; ++k) {
        const int lr = lane4r + 4 * k;
        f32x4 v = *(const f32x4*)&st[lr * 68 + lane16c * 4];
        const int grow = wrow0 + mp * 32 + lr;
        float* C = (float*)Cv + (size_t)bz * bsC;
        if constexpr (EPI == EPI_PRIOR) {
          const float4 p = *(const float4*)&prior[(size_t)grow * 1024 + gcol];
          v[0] += p.x; v[1] += p.y; v[2] += p.z; v[3] += p.w;
        }
        *(f32x4*)&C[(size_t)grow * N + gcol] = v;
      }
      wait_lgkm0();
    }
  } else {
    bf16* st = (bf16*)smem + wid * (32 * 72);
    const int lane8r = lane >> 3, lane8c = lane & 7;
#pragma unroll
    for (int mp = 0; mp < MF / 2; ++mp) {
#pragma unroll
      for (int mm = 0; mm < 2; ++mm) {
        const int m = mp * 2 + mm;
#pragma unroll
        for (int n = 0; n < 4; ++n) {
          const int col = ccol_base + n * 16 + l15;
          float bcol = 0.f, wcol = 0.f, bvcol = 0.f;
          if constexpr (EPI == EPI_DYT) { bcol = bias[col]; wcol = wv[col]; bvcol = bv[col]; }
          if constexpr (EPI == EPI_GELU) bcol = bias[col];
#pragma unroll
          for (int r = 0; r < 4; ++r) {
            const int lr = mm * 16 + (lhi << 2) + r;
            const float v = acc[m][n][r];
            bf16 o;
            if constexpr (EPI == EPI_DYT) {
              o = (bf16)(tanhf(a2v * (v + bcol)) * wcol + bvcol);
            } else if constexpr (EPI == EPI_GELU) {
              const float g = v + bcol;
              o = (bf16)(0.5f * g * (1.0f + erff(g * 0.70710678118654752f)));
            } else {
              o = (bf16)v;
            }
            st[lr * 72 + n * 16 + l15] = o;
          }
        }
      }
      wait_lgkm0();
      if constexpr (EPI == EPI_QKV) {
        if (ccol_base >= 2048) {
          // V third: write TRANSPOSED to Vt[b][d][t] at (bf16*)Cv + 2*bsC.
          // lane = d within the wave's 64-col chunk; 32 t-values per mp chunk
          // (t-chunk is 32-aligned so it never crosses a batch boundary).
          const int d = (ccol_base - 2048) + lane;
          const int grow0 = wrow0 + mp * 32;
          const int bb = grow0 >> 11;          // batch (T = 2048)
          const int tt = grow0 & 2047;
          bf16* VT = (bf16*)Cv + 2ull * (size_t)bsC +
                     (size_t)bb * 2097152ull + (size_t)d * 2048 + tt;
#pragma unroll
          for (int tq = 0; tq < 4; ++tq) {
            bf16x8 w;
#pragma unroll
            for (int j = 0; j < 8; ++j) w[j] = st[(tq * 8 + j) * 72 + lane];
            *(bf16x8*)&VT[tq * 8] = w;
          }
        } else {
          // Q / K thirds: row-major as before
          bf16* C = (bf16*)Cv + (size_t)(ccol_base >> 10) * bsC;
#pragma unroll
          for (int k = 0; k < 4; ++k) {
            const int lr = lane8r + 8 * k;
            const bf16x8 v = *(const bf16x8*)&st[lr * 72 + lane8c * 8];
            const int grow = wrow0 + mp * 32 + lr;
            *(bf16x8*)&C[(size_t)grow * 1024 + (ccol_base & 1023) + lane8c * 8] = v;
          }
        }
      } else {
#pragma unroll
        for (int k = 0; k < 4; ++k) {
          const int lr = lane8r + 8 * k;
          const bf16x8 v = *(const bf16x8*)&st[lr * 72 + lane8c * 8];
          const int grow = wrow0 + mp * 32 + lr;
          bf16* C = (bf16*)Cv + (size_t)bz * bsC;
          *(bf16x8*)&C[(size_t)grow * N + ccol_base + lane8c * 8] = v;
        }
      }
      wait_lgkm0();
    }
  }
}

// ---------------------------------------------------------------------------
// fused: xpe = x + pos_embed; prior = dyt3(xpe) (fp32); xn = dyt1(xpe) (bf16)
// ---------------------------------------------------------------------------
__global__ __launch_bounds__(256) void ew_pre(
    const float* __restrict__ x, const float* __restrict__ pe,
    const float* __restrict__ a1p, const float* __restrict__ w1, const float* __restrict__ b1,
    const float* __restrict__ a3p, const float* __restrict__ w3, const float* __restrict__ b3,
    float* __restrict__ prior, bf16* __restrict__ xn, int total4)
{
  const float a1 = a1p[0], a3 = a3p[0];
  for (int i = blockIdx.x * 256 + threadIdx.x; i < total4; i += gridDim.x * 256) {
    const int dq = i & 255;
    const float4 xv  = ((const float4*)x)[i];
    const float4 pv  = ((const float4*)pe)[dq];
    const float4 w1v = ((const float4*)w1)[dq];
    const float4 b1v = ((const float4*)b1)[dq];
    const float4 w3v = ((const float4*)w3)[dq];
    const float4 b3v = ((const float4*)b3)[dq];
    const float x0 = xv.x + pv.x, x1 = xv.y + pv.y, x2 = xv.z + pv.z, x3 = xv.w + pv.w;
    float4 prv;
    prv.x = tanhf(a3 * x0) * w3v.x + b3v.x;
    prv.y = tanhf(a3 * x1) * w3v.y + b3v.y;
    prv.z = tanhf(a3 * x2) * w3v.z + b3v.z;
    prv.w = tanhf(a3 * x3) * w3v.w + b3v.w;
    ((float4*)prior)[i] = prv;
    bf16x4 o;
    o[0] = (bf16)(tanhf(a1 * x0) * w1v.x + b1v.x);
    o[1] = (bf16)(tanhf(a1 * x1) * w1v.y + b1v.y);
    o[2] = (bf16)(tanhf(a1 * x2) * w1v.z + b1v.z);
    o[3] = (bf16)(tanhf(a1 * x3) * w1v.w + b1v.w);
    ((bf16x4*)xn)[i] = o;
  }
}

// fp32 -> bf16 weight conversion, 6 segments via blockIdx.y
__global__ __launch_bounds__(256) void conv_w(
    const float* __restrict__ s0, const float* __restrict__ s1, const float* __restrict__ s2,
    const float* __restrict__ s3, const float* __restrict__ s4, const float* __restrict__ s5,
    bf16* __restrict__ d0, bf16* __restrict__ d1, bf16* __restrict__ d2,
    bf16* __restrict__ d3, bf16* __restrict__ d4, bf16* __restrict__ d5,
    int n0, int n1, int n2, int n3, int n4, int n5)
{
  const float* s; bf16* d; int n;
  switch (blockIdx.y) {
    case 0: s = s0; d = d0; n = n0; break;
    case 1: s = s1; d = d1; n = n1; break;
    case 2: s = s2; d = d2; n = n2; break;
    case 3: s = s3; d = d3; n = n3; break;
    case 4: s = s4; d = d4; n = n4; break;
    default: s = s5; d = d5; n = n5; break;
  }
  const int nq = n >> 2;
  for (int i = blockIdx.x * 256 + threadIdx.x; i < nq; i += gridDim.x * 256) {
    const float4 v = ((const float4*)s)[i];
    bf16x4 o;
    o[0] = (bf16)v.x; o[1] = (bf16)v.y; o[2] = (bf16)v.z; o[3] = (bf16)v.w;
    ((bf16x4*)d)[i] = o;
  }
}

// ---------------------------------------------------------------------------
// reductions
// ---------------------------------------------------------------------------
DEVI float wave_red_max(float v) {
#pragma unroll
  for (int o = 32; o > 0; o >>= 1) v = fmaxf(v, __shfl_xor(v, o));
  return v;
}
DEVI float wave_red_sum(float v) {
#pragma unroll
  for (int o = 32; o > 0; o >>= 1) v += __shfl_xor(v, o);
  return v;
}
DEVI float block_red_max(float v, float* sm) {
  v = wave_red_max(v);
  if ((threadIdx.x & 63) == 0) sm[threadIdx.x >> 6] = v;
  __syncthreads();
  v = fmaxf(fmaxf(sm[0], sm[1]), fmaxf(sm[2], sm[3]));
  __syncthreads();
  return v;
}
DEVI float block_red_sum(float v, float* sm) {
  v = wave_red_sum(v);
  if ((threadIdx.x & 63) == 0) sm[threadIdx.x >> 6] = v;
  __syncthreads();
  v = sm[0] + sm[1] + sm[2] + sm[3];
  __syncthreads();
  return v;
}

// row softmax over 2048 scores (fp32 in) -> bf16 probs
__global__ __launch_bounds__(256) void softmax_k(const float* __restrict__ scores, bf16* __restrict__ probs) {
  __shared__ float sm[4];
  const size_t row = blockIdx.x;
  const float* s = scores + row * 2048;
  bf16* p = probs + row * 2048;
  const int t = threadIdx.x;
  const float4 v0 = *(const float4*)&s[t * 4];
  const float4 v1 = *(const float4*)&s[1024 + t * 4];
  float mx = fmaxf(fmaxf(fmaxf(v0.x, v0.y), fmaxf(v0.z, v0.w)),
                   fmaxf(fmaxf(v1.x, v1.y), fmaxf(v1.z, v1.w)));
  mx = block_red_max(mx, sm);
  const float e0 = expf(v0.x - mx), e1 = expf(v0.y - mx), e2 = expf(v0.z - mx), e3 = expf(v0.w - mx);
  const float e4 = expf(v1.x - mx), e5 = expf(v1.y - mx), e6 = expf(v1.z - mx), e7 = expf(v1.w - mx);
  float ssum = e0 + e1 + e2 + e3 + e4 + e5 + e6 + e7;
  ssum = block_red_sum(ssum, sm);
  const float inv = 1.0f / ssum;
  bf16x4 o0, o1;
  o0[0] = (bf16)(e0 * inv); o0[1] = (bf16)(e1 * inv); o0[2] = (bf16)(e2 * inv); o0[3] = (bf16)(e3 * inv);
  o1[0] = (bf16)(e4 * inv); o1[1] = (bf16)(e5 * inv); o1[2] = (bf16)(e6 * inv); o1[3] = (bf16)(e7 * inv);
  *(bf16x4*)&p[t * 4] = o0;
  *(bf16x4*)&p[1024 + t * 4] = o1;
}

// per-row JS pieces -> per-row partials
__global__ __launch_bounds__(256) void loss_k(const float* __restrict__ prior,
                                              const float* __restrict__ post,
                                              float* __restrict__ partial) {
  __shared__ float sm[4];
  const size_t row = blockIdx.x;
  const int t = threadIdx.x;
  const float4 pr = *(const float4*)&prior[row * 1024 + t * 4];
  const float4 po = *(const float4*)&post[row * 1024 + t * 4];
  float4 mm;
  mm.x = 0.5f * (pr.x + po.x); mm.y = 0.5f * (pr.y + po.y);
  mm.z = 0.5f * (pr.z + po.z); mm.w = 0.5f * (pr.w + po.w);
  const float mxp = block_red_max(fmaxf(fmaxf(pr.x, pr.y), fmaxf(pr.z, pr.w)), sm);
  const float mxo = block_red_max(fmaxf(fmaxf(po.x, po.y), fmaxf(po.z, po.w)), sm);
  const float mxm = block_red_max(fmaxf(fmaxf(mm.x, mm.y), fmaxf(mm.z, mm.w)), sm);
  float sp = expf(pr.x - mxp) + expf(pr.y - mxp) + expf(pr.z - mxp) + expf(pr.w - mxp);
  sp = block_red_sum(sp, sm);
  float so = expf(po.x - mxo) + expf(po.y - mxo) + expf(po.z - mxo) + expf(po.w - mxo);
  so = block_red_sum(so, sm);
  const float em0 = expf(mm.x - mxm), em1 = expf(mm.y - mxm), em2 = expf(mm.z - mxm), em3 = expf(mm.w - mxm);
  float smm = block_red_sum(em0 + em1 + em2 + em3, sm);
  const float invm = 1.0f / smm;
  float s1 = em0 * invm * (mm.x - pr.x) + em1 * invm * (mm.y - pr.y) +
             em2 * invm * (mm.z - pr.z) + em3 * invm * (mm.w - pr.w);
  float s2 = em0 * invm * (mm.x - po.x) + em1 * invm * (mm.y - po.y) +
             em2 * invm * (mm.z - po.z) + em3 * invm * (mm.w - po.w);
  s1 = block_red_sum(s1, sm);
  s2 = block_red_sum(s2, sm);
  if (t == 0) {
    const float logZp = mxp + logf(sp);
    const float logZo = mxo + logf(so);
    const float logZm = mxm + logf(smm);
    partial[row]        = s1 + (logZp - logZm);
    partial[8192 + row] = s2 + (logZo - logZm);
  }
}

__global__ __launch_bounds__(1024) void loss_fin(const float* __restrict__ partial,
                                                 float* __restrict__ out) {
  __shared__ float sm[32];
  const int t = threadIdx.x;
  float a = 0.f, b = 0.f;
  for (int i = t; i < 8192; i += 1024) {
    a += partial[i];
    b += partial[8192 + i];
  }
  float v = a + b;
#pragma unroll
  for (int o = 32; o > 0; o >>= 1) v += __shfl_xor(v, o);
  if ((t & 63) == 0) sm[t >> 6] = v;
  __syncthreads();
  if (t == 0) {
    float s = 0.f;
#pragma unroll
    for (int w = 0; w < 16; ++w) s += sm[w];
    out[0] = 0.125f * s;
  }
}

// ---------------------------------------------------------------------------
extern "C" void kernel_launch(void* const* d_in, const int* in_sizes, int n_in,
                              void* d_out, int out_size, void* d_ws, size_t ws_size,
                              hipStream_t stream) {
  const float* x  = (const float*)d_in[0];
  const float* pe = (const float*)d_in[1];
  const float* a1 = (const float*)d_in[2];
  const float* w1 = (const float*)d_in[3];
  const float* b1 = (const float*)d_in[4];
  const float* a2 = (const float*)d_in[5];
  const float* w2 = (const float*)d_in[6];
  const float* b2 = (const float*)d_in[7];
  const float* a3 = (const float*)d_in[8];
  const float* w3 = (const float*)d_in[9];
  const float* b3 = (const float*)d_in[10];
  const float* Wq = (const float*)d_in[11];
  const float* Wk = (const float*)d_in[12];
  const float* Wv = (const float*)d_in[13];
  const float* Wp = (const float*)d_in[14];
  const float* bp = (const float*)d_in[15];
  const float* We = (const float*)d_in[16];
  const float* be = (const float*)d_in[17];
  const float* Wc = (const float*)d_in[18];
  const float* bc = (const float*)d_in[19];
  float* out = (float*)d_out;

  char* ws = (char*)d_ws;
  float* prior  = (float*)(ws + 0);              // 33.55 MB fp32
  bf16*  xn     = (bf16*)(ws + 33554432ull);     // reused: attn out
  bf16*  Qb     = (bf16*)(ws + 50331648ull);     // Q; K at +bsC; Vt at +2*bsC
  bf16*  Kb     = (bf16*)(ws + 67108864ull);
  bf16*  Vt     = (bf16*)(ws + 83886080ull);     // V TRANSPOSED [B][D][T] (from QKV epi)
  float* scores = (float*)(ws + 117440512ull);   // reused: eb bf16, loss partials
  bf16*  Wqb    = (bf16*)(ws + 184549376ull);    // Wq/Wk/Wv contiguous
  bf16*  Wkb    = (bf16*)(ws + 186646528ull);
  bf16*  Wvb    = (bf16*)(ws + 188743680ull);
  bf16*  Wpb    = (bf16*)(ws + 190840832ull);
  bf16*  Web    = (bf16*)(ws + 192937984ull);
  bf16*  Wcb    = (bf16*)(ws + 201326592ull);
  bf16*  attno  = xn;
  bf16*  h2     = Qb;
  bf16*  eb     = (bf16*)scores;
  float* partial = (float*)(ws + 117440512ull);
  bf16*  probs  = (bf16*)d_out;

  static bool attr_done = false;
  if (!attr_done) {
    hipFuncSetAttribute((const void*)gemm2<EPI_QKV>,   hipFuncAttributeMaxDynamicSharedMemorySize, 73728);
    hipFuncSetAttribute((const void*)gemm2<EPI_SCORES>,hipFuncAttributeMaxDynamicSharedMemorySize, 73728);
    hipFuncSetAttribute((const void*)gemm2<EPI_BF16>,  hipFuncAttributeMaxDynamicSharedMemorySize, 73728);
    hipFuncSetAttribute((const void*)gemm2<EPI_DYT>,   hipFuncAttributeMaxDynamicSharedMemorySize, 73728);
    hipFuncSetAttribute((const void*)gemm2<EPI_GELU>,  hipFuncAttributeMaxDynamicSharedMemorySize, 73728);
    hipFuncSetAttribute((const void*)gemm2<EPI_PRIOR>, hipFuncAttributeMaxDynamicSharedMemorySize, 73728);
    attr_done = true;
  }

  dim3 blk(256);
  dim3 gblk(512);
  constexpr unsigned SH = 73728;   // ring-3 * 24KB -> 2 blocks/CU

  conv_w<<<dim3(1024, 6), blk, 0, stream>>>(Wq, Wk, Wv, Wp, We, Wc,
                                            Wqb, Wkb, Wvb, Wpb, Web, Wcb,
                                            1048576, 1048576, 1048576, 1048576, 4194304, 4194304);
  ew_pre<<<2048, blk, 0, stream>>>(x, pe, a1, w1, b1, a3, w3, b3, prior, xn, 2097152);

  // fused QKV: [8192,3072] = xn @ [Wq;Wk;Wv]^T; V third written transposed
  gemm2<EPI_QKV><<<dim3(12, 64, 1), gblk, SH, stream>>>(xn, Wqb, Qb, 3072, 1024,
      0, 0, 8388608ll, nullptr, nullptr, nullptr, nullptr, nullptr, 0.f);

  // scores[b,t,s] = (Q·K)/32 - |t-s|
  gemm2<EPI_SCORES><<<dim3(8, 16, 4), gblk, SH, stream>>>(Qb, Kb, scores, 2048, 1024,
      2097152ll, 2097152ll, 4194304ll, nullptr, nullptr, nullptr, nullptr, nullptr, 0.03125f);
  softmax_k<<<8192, blk, 0, stream>>>(scores, probs);

  // out[b,t,d] = probs @ Vt
  gemm2<EPI_BF16><<<dim3(4, 16, 4), gblk, SH, stream>>>(probs, Vt, attno, 1024, 2048,
      4194304ll, 2097152ll, 2097152ll, nullptr, nullptr, nullptr, nullptr, nullptr, 0.f);

  // proj + dyt2
  gemm2<EPI_DYT><<<dim3(4, 64, 1), gblk, SH, stream>>>(attno, Wpb, h2, 1024, 1024,
      0, 0, 0, bp, a2, w2, b2, nullptr, 0.f);
  // expand + exact gelu
  gemm2<EPI_GELU><<<dim3(16, 64, 1), gblk, SH, stream>>>(h2, Web, eb, 4096, 1024,
      0, 0, 0, be, nullptr, nullptr, nullptr, nullptr, 0.f);
  // contract + bias + prior -> posterior
  gemm2<EPI_PRIOR><<<dim3(4, 64, 1), gblk, SH, stream>>>(eb, Wcb, out, 1024, 4096,
      0, 0, 0, bc, nullptr, nullptr, nullptr, prior, 0.f);

  loss_k<<<8192, blk, 0, stream>>>(prior, out, partial);
  loss_fin<<<1, 1024, 0, stream>>>(partial, out + 8388608);
}

// Round 12
// 403.927 us; speedup vs baseline: 1.0641x; 1.0254x over previous
//
#include <hip/hip_runtime.h>
#include <cstdint>
#include <cstddef>

typedef __bf16 bf16;
typedef __bf16 bf16x4 __attribute__((ext_vector_type(4)));
typedef __bf16 bf16x8 __attribute__((ext_vector_type(8)));
typedef float  f32x4 __attribute__((ext_vector_type(4)));

#define DEVI __device__ __forceinline__

// ---------------------------------------------------------------------------
// async global->LDS (16B per lane)
// ---------------------------------------------------------------------------
DEVI void async_ld16(void* lds, const void* g) {
  const __attribute__((address_space(1))) uint32_t* g1 =
      reinterpret_cast<const __attribute__((address_space(1))) uint32_t*>(
          reinterpret_cast<uintptr_t>(g));
  uint32_t lo = (uint32_t)reinterpret_cast<uintptr_t>(lds);
  __attribute__((address_space(3))) uint32_t* l3 =
      reinterpret_cast<__attribute__((address_space(3))) uint32_t*>(lo);
  __builtin_amdgcn_global_load_lds(g1, l3, 16, 0, 0);
}

template <int N> DEVI void wait_vmcnt() {
  asm volatile("s_waitcnt vmcnt(%0)" :: "n"(N) : "memory");
}
DEVI void blk_barrier() {
  asm volatile("" ::: "memory");
  __builtin_amdgcn_s_barrier();
  asm volatile("" ::: "memory");
}
DEVI void wait_lgkm0() {
  asm volatile("s_waitcnt lgkmcnt(0)" ::: "memory");
}

enum { EPI_PV = 0, EPI_QKV = 1, EPI_SCORES = 2, EPI_DYT = 3, EPI_GELU = 4, EPI_PRIOR = 5 };

// ---------------------------------------------------------------------------
// B^T GEMM: C[row,col] = sum_k A[row,k]*B[col,k]   (R5 structure, best
// measured). BM=128, BN=256, BK=32, 8 waves (512 thr, 2Mx4N), ring-3 LDS
// (72KB), 2 blocks/CU. Counted vmcnt, raw s_barrier x2/K-tile, setprio.
// K-octet XOR swizzle both sides. Coalesced LDS-staged epilogue.
// R10: EPI_QKV writes V third transposed (Vt at Cv + 2*bsC).
// R11: EPI_SCORES writes bf16 e = exp(score - m[row]) (m = diag shift, safe
//      upper-bound-ish: |content/32| << 1 <= |t-s|) + fp32 rowsum atomics.
//      EPI_PV normalizes by 1/rowsum[row] in the epilogue. Softmax kernel
//      and the 67MB fp32 scores round-trip are eliminated.
//   param aliasing: EPI_SCORES: al = m[], bv = rowsum (atomic);
//                   EPI_PV:     al = rowsum (read).
// ---------------------------------------------------------------------------
template <int EPI>
__global__ __launch_bounds__(512, 4) void gemm2(
    const bf16* __restrict__ A, const bf16* __restrict__ Bm, void* __restrict__ Cv,
    int N, int K,
    long long bsA, long long bsB, long long bsC,
    const float* __restrict__ bias, const float* __restrict__ al,
    const float* __restrict__ wv, const float* __restrict__ bv,
    const float* __restrict__ prior, float scale)
{
  constexpr int BM = 128;
  constexpr int BN = 256;
  constexpr int BK = 32;
  constexpr int ASZ = BM * BK;          // 4096 elems
  constexpr int SLOT = ASZ + BN * BK;   // 12288 elems = 24KB
  constexpr int L = 3;                  // loads per thread per tile (1 A + 2 B)
  constexpr int MF = 4;                 // m-frags per wave (128/2/16)

  extern __shared__ __align__(16) bf16 smem[];  // 3 * SLOT

  const int tid = threadIdx.x;

  // T1 XCD-chunked swizzle (nwg always a multiple of 8)
  const int gx = gridDim.x, gy = gridDim.y;
  const int nwg = gx * gy * gridDim.z;
  int id = (blockIdx.z * gy + blockIdx.y) * gx + blockIdx.x;
  id = (id & 7) * (nwg >> 3) + (id >> 3);
  const int bx = id % gx;
  const int t1 = id / gx;
  const int by = t1 % gy;
  const int bz = t1 / gy;

  const bf16* Ab = A  + (size_t)bz * bsA + (size_t)by * BM * K;
  const bf16* Bb = Bm + (size_t)bz * bsB + (size_t)bx * BN * K;

  const int lane = tid & 63;
  const int wid  = tid >> 6;
  const int l15 = lane & 15;
  const int lhi = lane >> 4;
  const int wr = (wid >> 2) * 64;
  const int wc = (wid & 3) * 64;

  // staging: thread -> (row = tid>>2, slot p = tid&3); LDS dst linear in lane.
  const int srow = tid >> 2;
  const int sp   = tid & 3;
  const int soct = (sp ^ ((srow >> 1) & 3)) << 3;
  const bf16* aSrc  = Ab + (size_t)srow * K + soct;
  const bf16* bSrc0 = Bb + (size_t)srow * K + soct;
  const bf16* bSrc1 = Bb + (size_t)(srow + 128) * K + soct;
  const int dstA = tid * 8;
  const int dstB0 = ASZ + tid * 8;
  const int dstB1 = ASZ + 4096 + tid * 8;

  const int koff = ((lhi ^ ((l15 >> 1) & 3)) << 3);

  f32x4 acc[MF][4];
  const f32x4 zero = {0.f, 0.f, 0.f, 0.f};
#pragma unroll
  for (int m = 0; m < MF; ++m)
#pragma unroll
    for (int n = 0; n < 4; ++n) acc[m][n] = zero;

  const int NT = K / BK;

  auto STAGE = [&](int t) {
    bf16* dst = smem + (size_t)(t % 3) * SLOT;
    const size_t kb = (size_t)t * BK;
    async_ld16(dst + dstA,  aSrc  + kb);
    async_ld16(dst + dstB0, bSrc0 + kb);
    async_ld16(dst + dstB1, bSrc1 + kb);
  };

  auto COMPUTE = [&](int t) {
    const bf16* buf = smem + (size_t)(t % 3) * SLOT;
    bf16x8 bf_[4];
#pragma unroll
    for (int n = 0; n < 4; ++n)
      bf_[n] = *(const bf16x8*)&buf[ASZ + (wc + n * 16 + l15) * BK + koff];
    __builtin_amdgcn_s_setprio(1);
#pragma unroll
    for (int m = 0; m < MF; ++m) {
      const bf16x8 af_ = *(const bf16x8*)&buf[(wr + m * 16 + l15) * BK + koff];
#pragma unroll
      for (int n = 0; n < 4; ++n)
        acc[m][n] = __builtin_amdgcn_mfma_f32_16x16x32_bf16(af_, bf_[n], acc[m][n], 0, 0, 0);
    }
    __builtin_amdgcn_s_setprio(0);
  };

  STAGE(0); STAGE(1);

  for (int t = 0; t < NT - 2; ++t) {
    STAGE(t + 2);
    wait_vmcnt<2 * L>();
    blk_barrier();
    COMPUTE(t);
    blk_barrier();
  }
  wait_vmcnt<L>(); blk_barrier(); COMPUTE(NT - 2); blk_barrier();
  wait_vmcnt<0>(); blk_barrier(); COMPUTE(NT - 1);

  // ---------------- epilogue: LDS-staged, coalesced ----------------
  __syncthreads();

  const int ccol_base = bx * BN + wc;
  const int wrow0 = by * BM + wr;

  float a2v = 0.f;
  if constexpr (EPI == EPI_DYT) a2v = al[0];

  if constexpr (EPI == EPI_PRIOR) {
    float* st = (float*)smem + wid * (32 * 68);
    const int lane4r = lane >> 4, lane16c = lane & 15;
    const int gcol = ccol_base + lane16c * 4;
#pragma unroll
    for (int mp = 0; mp < MF / 2; ++mp) {
#pragma unroll
      for (int mm = 0; mm < 2; ++mm) {
        const int m = mp * 2 + mm;
#pragma unroll
        for (int n = 0; n < 4; ++n) {
          const int col = ccol_base + n * 16 + l15;
          const float bcol = bias[col];
#pragma unroll
          for (int r = 0; r < 4; ++r) {
            const int lr = mm * 16 + (lhi << 2) + r;
            st[lr * 68 + n * 16 + l15] = acc[m][n][r] + bcol;
          }
        }
      }
      wait_lgkm0();
#pragma unroll
      for (int k = 0; k < 8; ++k) {
        const int lr = lane4r + 4 * k;
        f32x4 v = *(const f32x4*)&st[lr * 68 + lane16c * 4];
        const int grow = wrow0 + mp * 32 + lr;
        float* C = (float*)Cv + (size_t)bz * bsC;
        const float4 p = *(const float4*)&prior[(size_t)grow * 1024 + gcol];
        v[0] += p.x; v[1] += p.y; v[2] += p.z; v[3] += p.w;
        *(f32x4*)&C[(size_t)grow * N + gcol] = v;
      }
      wait_lgkm0();
    }
  } else {
    bf16* st = (bf16*)smem + wid * (32 * 72);
    const int lane8r = lane >> 3, lane8c = lane & 7;
#pragma unroll
    for (int mp = 0; mp < MF / 2; ++mp) {
#pragma unroll
      for (int mm = 0; mm < 2; ++mm) {
        const int m = mp * 2 + mm;
        float mv[4];
        if constexpr (EPI == EPI_SCORES) {
#pragma unroll
          for (int r = 0; r < 4; ++r)
            mv[r] = al[(size_t)bz * 2048 + wrow0 + mp * 32 + mm * 16 + (lhi << 2) + r];
        }
        if constexpr (EPI == EPI_PV) {
#pragma unroll
          for (int r = 0; r < 4; ++r)
            mv[r] = 1.0f / al[(size_t)bz * 2048 + wrow0 + mp * 32 + mm * 16 + (lhi << 2) + r];
        }
#pragma unroll
        for (int n = 0; n < 4; ++n) {
          const int col = ccol_base + n * 16 + l15;
          float bcol = 0.f, wcol = 0.f, bvcol = 0.f;
          if constexpr (EPI == EPI_DYT) { bcol = bias[col]; wcol = wv[col]; bvcol = bv[col]; }
          if constexpr (EPI == EPI_GELU) bcol = bias[col];
#pragma unroll
          for (int r = 0; r < 4; ++r) {
            const int lr = mm * 16 + (lhi << 2) + r;
            const float v = acc[m][n][r];
            bf16 o;
            if constexpr (EPI == EPI_DYT) {
              o = (bf16)(tanhf(a2v * (v + bcol)) * wcol + bvcol);
            } else if constexpr (EPI == EPI_GELU) {
              const float g = v + bcol;
              o = (bf16)(0.5f * g * (1.0f + erff(g * 0.70710678118654752f)));
            } else if constexpr (EPI == EPI_SCORES) {
              const int row = wrow0 + mp * 32 + lr;
              o = (bf16)__expf(v * scale - fabsf((float)(row - col)) - mv[r]);
            } else if constexpr (EPI == EPI_PV) {
              o = (bf16)(v * mv[r]);
            } else {
              o = (bf16)v;
            }
            st[lr * 72 + n * 16 + l15] = o;
          }
        }
      }
      wait_lgkm0();
      if constexpr (EPI == EPI_QKV) {
        if (ccol_base >= 2048) {
          // V third: write TRANSPOSED to Vt[b][d][t] at (bf16*)Cv + 2*bsC.
          const int d = (ccol_base - 2048) + lane;
          const int grow0 = wrow0 + mp * 32;
          const int bb = grow0 >> 11;
          const int tt = grow0 & 2047;
          bf16* VT = (bf16*)Cv + 2ull * (size_t)bsC +
                     (size_t)bb * 2097152ull + (size_t)d * 2048 + tt;
#pragma unroll
          for (int tq = 0; tq < 4; ++tq) {
            bf16x8 w;
#pragma unroll
            for (int j = 0; j < 8; ++j) w[j] = st[(tq * 8 + j) * 72 + lane];
            *(bf16x8*)&VT[tq * 8] = w;
          }
        } else {
          bf16* C = (bf16*)Cv + (size_t)(ccol_base >> 10) * bsC;
#pragma unroll
          for (int k = 0; k < 4; ++k) {
            const int lr = lane8r + 8 * k;
            const bf16x8 v = *(const bf16x8*)&st[lr * 72 + lane8c * 8];
            const int grow = wrow0 + mp * 32 + lr;
            *(bf16x8*)&C[(size_t)grow * 1024 + (ccol_base & 1023) + lane8c * 8] = v;
          }
        }
      } else {
#pragma unroll
        for (int k = 0; k < 4; ++k) {
          const int lr = lane8r + 8 * k;
          const bf16x8 v = *(const bf16x8*)&st[lr * 72 + lane8c * 8];
          const int grow = wrow0 + mp * 32 + lr;
          bf16* C = (bf16*)Cv + (size_t)bz * bsC;
          *(bf16x8*)&C[(size_t)grow * N + ccol_base + lane8c * 8] = v;
          if constexpr (EPI == EPI_SCORES) {
            // fp32 rowsum partial: reduce this thread's 8 cols + 8-lane group
            float s = 0.f;
#pragma unroll
            for (int j = 0; j < 8; ++j) s += (float)v[j];
            s += __shfl_xor(s, 1);
            s += __shfl_xor(s, 2);
            s += __shfl_xor(s, 4);
            if (lane8c == 0)
              atomicAdd(const_cast<float*>(bv) + (size_t)bz * 2048 + grow, s);
          }
        }
      }
      wait_lgkm0();
    }
  }
}

// ---------------------------------------------------------------------------
// reductions
// ---------------------------------------------------------------------------
DEVI float wave_red_sum(float v) {
#pragma unroll
  for (int o = 32; o > 0; o >>= 1) v += __shfl_xor(v, o);
  return v;
}
DEVI float wave_red_max(float v) {
#pragma unroll
  for (int o = 32; o > 0; o >>= 1) v = fmaxf(v, __shfl_xor(v, o));
  return v;
}
DEVI float block_red_max(float v, float* sm) {
  v = wave_red_max(v);
  if ((threadIdx.x & 63) == 0) sm[threadIdx.x >> 6] = v;
  __syncthreads();
  v = fmaxf(fmaxf(sm[0], sm[1]), fmaxf(sm[2], sm[3]));
  __syncthreads();
  return v;
}
DEVI float block_red_sum(float v, float* sm) {
  v = wave_red_sum(v);
  if ((threadIdx.x & 63) == 0) sm[threadIdx.x >> 6] = v;
  __syncthreads();
  v = sm[0] + sm[1] + sm[2] + sm[3];
  __syncthreads();
  return v;
}

// diag shift: m[row] = (Q_row . K_row) * scale   (one wave per row)
__global__ __launch_bounds__(256) void diag_k(const bf16* __restrict__ Q,
                                              const bf16* __restrict__ K,
                                              float* __restrict__ m, float scale) {
  const int row = blockIdx.x * 4 + (threadIdx.x >> 6);
  const int lane = threadIdx.x & 63;
  const bf16* q = Q + (size_t)row * 1024 + lane * 16;
  const bf16* k = K + (size_t)row * 1024 + lane * 16;
  float s = 0.f;
#pragma unroll
  for (int j = 0; j < 2; ++j) {
    const bf16x8 qv = *(const bf16x8*)(q + j * 8);
    const bf16x8 kv = *(const bf16x8*)(k + j * 8);
#pragma unroll
    for (int e = 0; e < 8; ++e) s += (float)qv[e] * (float)kv[e];
  }
  s = wave_red_sum(s);
  if (lane == 0) m[row] = s * scale;
}

// ---------------------------------------------------------------------------
// fused: xpe = x + pos_embed; prior = dyt3(xpe) (fp32); xn = dyt1(xpe) (bf16)
// ---------------------------------------------------------------------------
__global__ __launch_bounds__(256) void ew_pre(
    const float* __restrict__ x, const float* __restrict__ pe,
    const float* __restrict__ a1p, const float* __restrict__ w1, const float* __restrict__ b1,
    const float* __restrict__ a3p, const float* __restrict__ w3, const float* __restrict__ b3,
    float* __restrict__ prior, bf16* __restrict__ xn, int total4)
{
  const float a1 = a1p[0], a3 = a3p[0];
  for (int i = blockIdx.x * 256 + threadIdx.x; i < total4; i += gridDim.x * 256) {
    const int dq = i & 255;
    const float4 xv  = ((const float4*)x)[i];
    const float4 pv  = ((const float4*)pe)[dq];
    const float4 w1v = ((const float4*)w1)[dq];
    const float4 b1v = ((const float4*)b1)[dq];
    const float4 w3v = ((const float4*)w3)[dq];
    const float4 b3v = ((const float4*)b3)[dq];
    const float x0 = xv.x + pv.x, x1 = xv.y + pv.y, x2 = xv.z + pv.z, x3 = xv.w + pv.w;
    float4 prv;
    prv.x = tanhf(a3 * x0) * w3v.x + b3v.x;
    prv.y = tanhf(a3 * x1) * w3v.y + b3v.y;
    prv.z = tanhf(a3 * x2) * w3v.z + b3v.z;
    prv.w = tanhf(a3 * x3) * w3v.w + b3v.w;
    ((float4*)prior)[i] = prv;
    bf16x4 o;
    o[0] = (bf16)(tanhf(a1 * x0) * w1v.x + b1v.x);
    o[1] = (bf16)(tanhf(a1 * x1) * w1v.y + b1v.y);
    o[2] = (bf16)(tanhf(a1 * x2) * w1v.z + b1v.z);
    o[3] = (bf16)(tanhf(a1 * x3) * w1v.w + b1v.w);
    ((bf16x4*)xn)[i] = o;
  }
}

// fp32 -> bf16 weight conversion, 6 segments via blockIdx.y
__global__ __launch_bounds__(256) void conv_w(
    const float* __restrict__ s0, const float* __restrict__ s1, const float* __restrict__ s2,
    const float* __restrict__ s3, const float* __restrict__ s4, const float* __restrict__ s5,
    bf16* __restrict__ d0, bf16* __restrict__ d1, bf16* __restrict__ d2,
    bf16* __restrict__ d3, bf16* __restrict__ d4, bf16* __restrict__ d5,
    int n0, int n1, int n2, int n3, int n4, int n5)
{
  const float* s; bf16* d; int n;
  switch (blockIdx.y) {
    case 0: s = s0; d = d0; n = n0; break;
    case 1: s = s1; d = d1; n = n1; break;
    case 2: s = s2; d = d2; n = n2; break;
    case 3: s = s3; d = d3; n = n3; break;
    case 4: s = s4; d = d4; n = n4; break;
    default: s = s5; d = d5; n = n5; break;
  }
  const int nq = n >> 2;
  for (int i = blockIdx.x * 256 + threadIdx.x; i < nq; i += gridDim.x * 256) {
    const float4 v = ((const float4*)s)[i];
    bf16x4 o;
    o[0] = (bf16)v.x; o[1] = (bf16)v.y; o[2] = (bf16)v.z; o[3] = (bf16)v.w;
    ((bf16x4*)d)[i] = o;
  }
}

// per-row JS pieces -> per-row partials
__global__ __launch_bounds__(256) void loss_k(const float* __restrict__ prior,
                                              const float* __restrict__ post,
                                              float* __restrict__ partial) {
  __shared__ float sm[4];
  const size_t row = blockIdx.x;
  const int t = threadIdx.x;
  const float4 pr = *(const float4*)&prior[row * 1024 + t * 4];
  const float4 po = *(const float4*)&post[row * 1024 + t * 4];
  float4 mm;
  mm.x = 0.5f * (pr.x + po.x); mm.y = 0.5f * (pr.y + po.y);
  mm.z = 0.5f * (pr.z + po.z); mm.w = 0.5f * (pr.w + po.w);
  const float mxp = block_red_max(fmaxf(fmaxf(pr.x, pr.y), fmaxf(pr.z, pr.w)), sm);
  const float mxo = block_red_max(fmaxf(fmaxf(po.x, po.y), fmaxf(po.z, po.w)), sm);
  const float mxm = block_red_max(fmaxf(fmaxf(mm.x, mm.y), fmaxf(mm.z, mm.w)), sm);
  float sp = expf(pr.x - mxp) + expf(pr.y - mxp) + expf(pr.z - mxp) + expf(pr.w - mxp);
  sp = block_red_sum(sp, sm);
  float so = expf(po.x - mxo) + expf(po.y - mxo) + expf(po.z - mxo) + expf(po.w - mxo);
  so = block_red_sum(so, sm);
  const float em0 = expf(mm.x - mxm), em1 = expf(mm.y - mxm), em2 = expf(mm.z - mxm), em3 = expf(mm.w - mxm);
  float smm = block_red_sum(em0 + em1 + em2 + em3, sm);
  const float invm = 1.0f / smm;
  float s1 = em0 * invm * (mm.x - pr.x) + em1 * invm * (mm.y - pr.y) +
             em2 * invm * (mm.z - pr.z) + em3 * invm * (mm.w - pr.w);
  float s2 = em0 * invm * (mm.x - po.x) + em1 * invm * (mm.y - po.y) +
             em2 * invm * (mm.z - po.z) + em3 * invm * (mm.w - po.w);
  s1 = block_red_sum(s1, sm);
  s2 = block_red_sum(s2, sm);
  if (t == 0) {
    const float logZp = mxp + logf(sp);
    const float logZo = mxo + logf(so);
    const float logZm = mxm + logf(smm);
    partial[row]        = s1 + (logZp - logZm);
    partial[8192 + row] = s2 + (logZo - logZm);
  }
}

__global__ __launch_bounds__(1024) void loss_fin(const float* __restrict__ partial,
                                                 float* __restrict__ out) {
  __shared__ float sm[32];
  const int t = threadIdx.x;
  float a = 0.f, b = 0.f;
  for (int i = t; i < 8192; i += 1024) {
    a += partial[i];
    b += partial[8192 + i];
  }
  float v = a + b;
#pragma unroll
  for (int o = 32; o > 0; o >>= 1) v += __shfl_xor(v, o);
  if ((t & 63) == 0) sm[t >> 6] = v;
  __syncthreads();
  if (t == 0) {
    float s = 0.f;
#pragma unroll
    for (int w = 0; w < 16; ++w) s += sm[w];
    out[0] = 0.125f * s;
  }
}

// ---------------------------------------------------------------------------
extern "C" void kernel_launch(void* const* d_in, const int* in_sizes, int n_in,
                              void* d_out, int out_size, void* d_ws, size_t ws_size,
                              hipStream_t stream) {
  const float* x  = (const float*)d_in[0];
  const float* pe = (const float*)d_in[1];
  const float* a1 = (const float*)d_in[2];
  const float* w1 = (const float*)d_in[3];
  const float* b1 = (const float*)d_in[4];
  const float* a2 = (const float*)d_in[5];
  const float* w2 = (const float*)d_in[6];
  const float* b2 = (const float*)d_in[7];
  const float* a3 = (const float*)d_in[8];
  const float* w3 = (const float*)d_in[9];
  const float* b3 = (const float*)d_in[10];
  const float* Wq = (const float*)d_in[11];
  const float* Wk = (const float*)d_in[12];
  const float* Wv = (const float*)d_in[13];
  const float* Wp = (const float*)d_in[14];
  const float* bp = (const float*)d_in[15];
  const float* We = (const float*)d_in[16];
  const float* be = (const float*)d_in[17];
  const float* Wc = (const float*)d_in[18];
  const float* bc = (const float*)d_in[19];
  float* out = (float*)d_out;

  char* ws = (char*)d_ws;
  float* prior  = (float*)(ws + 0);              // 33.55 MB fp32
  bf16*  xn     = (bf16*)(ws + 33554432ull);     // reused: attn out
  bf16*  Qb     = (bf16*)(ws + 50331648ull);     // Q; K at +bsC; Vt at +2*bsC
  bf16*  Kb     = (bf16*)(ws + 67108864ull);
  bf16*  Vt     = (bf16*)(ws + 83886080ull);     // V TRANSPOSED [B][D][T]
  float* rowsum = (float*)(ws + 100663296ull);   // 32KB (freed Vb-era gap)
  float* mvec   = (float*)(ws + 100728832ull);   // 32KB diag shift
  float* scores = (float*)(ws + 117440512ull);   // eb bf16 region, loss partials
  bf16*  Wqb    = (bf16*)(ws + 184549376ull);    // Wq/Wk/Wv contiguous
  bf16*  Wkb    = (bf16*)(ws + 186646528ull);
  bf16*  Wvb    = (bf16*)(ws + 188743680ull);
  bf16*  Wpb    = (bf16*)(ws + 190840832ull);
  bf16*  Web    = (bf16*)(ws + 192937984ull);
  bf16*  Wcb    = (bf16*)(ws + 201326592ull);
  bf16*  attno  = xn;
  bf16*  h2     = Qb;
  bf16*  eb     = (bf16*)scores;
  float* partial = (float*)(ws + 117440512ull);
  bf16*  probs  = (bf16*)d_out;  // unnormalized exp scores (bf16), consumed by PV

  static bool attr_done = false;
  if (!attr_done) {
    hipFuncSetAttribute((const void*)gemm2<EPI_QKV>,   hipFuncAttributeMaxDynamicSharedMemorySize, 73728);
    hipFuncSetAttribute((const void*)gemm2<EPI_SCORES>,hipFuncAttributeMaxDynamicSharedMemorySize, 73728);
    hipFuncSetAttribute((const void*)gemm2<EPI_PV>,    hipFuncAttributeMaxDynamicSharedMemorySize, 73728);
    hipFuncSetAttribute((const void*)gemm2<EPI_DYT>,   hipFuncAttributeMaxDynamicSharedMemorySize, 73728);
    hipFuncSetAttribute((const void*)gemm2<EPI_GELU>,  hipFuncAttributeMaxDynamicSharedMemorySize, 73728);
    hipFuncSetAttribute((const void*)gemm2<EPI_PRIOR>, hipFuncAttributeMaxDynamicSharedMemorySize, 73728);
    attr_done = true;
  }

  dim3 blk(256);
  dim3 gblk(512);
  constexpr unsigned SH = 73728;   // ring-3 * 24KB -> 2 blocks/CU

  conv_w<<<dim3(1024, 6), blk, 0, stream>>>(Wq, Wk, Wv, Wp, We, Wc,
                                            Wqb, Wkb, Wvb, Wpb, Web, Wcb,
                                            1048576, 1048576, 1048576, 1048576, 4194304, 4194304);
  ew_pre<<<2048, blk, 0, stream>>>(x, pe, a1, w1, b1, a3, w3, b3, prior, xn, 2097152);

  // fused QKV: [8192,3072] = xn @ [Wq;Wk;Wv]^T; V third written transposed
  gemm2<EPI_QKV><<<dim3(12, 64, 1), gblk, SH, stream>>>(xn, Wqb, Qb, 3072, 1024,
      0, 0, 8388608ll, nullptr, nullptr, nullptr, nullptr, nullptr, 0.f);

  // diag shift m[row] = (Q_row . K_row)/32
  diag_k<<<2048, blk, 0, stream>>>(Qb, Kb, mvec, 0.03125f);
  hipMemsetAsync(rowsum, 0, 8192 * sizeof(float), stream);

  // e[b,t,s] = exp((Q.K)/32 - |t-s| - m[t])  (bf16) + fp32 rowsum atomics
  gemm2<EPI_SCORES><<<dim3(8, 16, 4), gblk, SH, stream>>>(Qb, Kb, probs, 2048, 1024,
      2097152ll, 2097152ll, 4194304ll, nullptr, mvec, nullptr, rowsum, nullptr, 0.03125f);

  // out[b,t,d] = (e @ Vt) / rowsum[t]
  gemm2<EPI_PV><<<dim3(4, 16, 4), gblk, SH, stream>>>(probs, Vt, attno, 1024, 2048,
      4194304ll, 2097152ll, 2097152ll, nullptr, rowsum, nullptr, nullptr, nullptr, 0.f);

  // proj + dyt2
  gemm2<EPI_DYT><<<dim3(4, 64, 1), gblk, SH, stream>>>(attno, Wpb, h2, 1024, 1024,
      0, 0, 0, bp, a2, w2, b2, nullptr, 0.f);
  // expand + exact gelu
  gemm2<EPI_GELU><<<dim3(16, 64, 1), gblk, SH, stream>>>(h2, Web, eb, 4096, 1024,
      0, 0, 0, be, nullptr, nullptr, nullptr, nullptr, 0.f);
  // contract + bias + prior -> posterior
  gemm2<EPI_PRIOR><<<dim3(4, 64, 1), gblk, SH, stream>>>(eb, Wcb, out, 1024, 4096,
      0, 0, 0, bc, nullptr, nullptr, nullptr, prior, 0.f);

  loss_k<<<8192, blk, 0, stream>>>(prior, out, partial);
  loss_fin<<<1, 1024, 0, stream>>>(partial, out + 8388608);
}

// Round 13
// 397.181 us; speedup vs baseline: 1.0822x; 1.0170x over previous
//
#include <hip/hip_runtime.h>
#include <cstdint>
#include <cstddef>

typedef __bf16 bf16;
typedef __bf16 bf16x4 __attribute__((ext_vector_type(4)));
typedef __bf16 bf16x8 __attribute__((ext_vector_type(8)));
typedef float  f32x4 __attribute__((ext_vector_type(4)));

#define DEVI __device__ __forceinline__

// ---------------------------------------------------------------------------
// async global->LDS (16B per lane)
// ---------------------------------------------------------------------------
DEVI void async_ld16(void* lds, const void* g) {
  const __attribute__((address_space(1))) uint32_t* g1 =
      reinterpret_cast<const __attribute__((address_space(1))) uint32_t*>(
          reinterpret_cast<uintptr_t>(g));
  uint32_t lo = (uint32_t)reinterpret_cast<uintptr_t>(lds);
  __attribute__((address_space(3))) uint32_t* l3 =
      reinterpret_cast<__attribute__((address_space(3))) uint32_t*>(lo);
  __builtin_amdgcn_global_load_lds(g1, l3, 16, 0, 0);
}

template <int N> DEVI void wait_vmcnt() {
  asm volatile("s_waitcnt vmcnt(%0)" :: "n"(N) : "memory");
}
DEVI void blk_barrier() {
  asm volatile("" ::: "memory");
  __builtin_amdgcn_s_barrier();
  asm volatile("" ::: "memory");
}
DEVI void wait_lgkm0() {
  asm volatile("s_waitcnt lgkmcnt(0)" ::: "memory");
}

enum { EPI_PV = 0, EPI_QKV = 1, EPI_SCORES = 2, EPI_DYT = 3, EPI_GELU = 4, EPI_PRIOR = 5 };

// ---------------------------------------------------------------------------
// B^T GEMM: C[row,col] = sum_k A[row,k]*B[col,k]   (R5 structure, best
// measured). BM=128, BN=256, BK=32, 8 waves (512 thr, 2Mx4N), ring-3 LDS
// (72KB), 2 blocks/CU. Counted vmcnt, raw s_barrier x2/K-tile, setprio.
// K-octet XOR swizzle both sides. Coalesced LDS-staged epilogue.
// R10: EPI_QKV writes V third transposed (Vt at Cv + 2*bsC).
// R11: EPI_SCORES writes bf16 e = exp(score - m[row]); EPI_PV normalizes by
//      1/rowsum[row]. R12: prior is bf16 (halves its traffic).
//   param aliasing: EPI_SCORES: al = m[], bv = rowsum (atomic);
//                   EPI_PV:     al = rowsum (read);
//                   EPI_PRIOR:  prior = bf16 residual (cast inside).
// ---------------------------------------------------------------------------
template <int EPI>
__global__ __launch_bounds__(512, 4) void gemm2(
    const bf16* __restrict__ A, const bf16* __restrict__ Bm, void* __restrict__ Cv,
    int N, int K,
    long long bsA, long long bsB, long long bsC,
    const float* __restrict__ bias, const float* __restrict__ al,
    const float* __restrict__ wv, const float* __restrict__ bv,
    const void* __restrict__ prior, float scale)
{
  constexpr int BM = 128;
  constexpr int BN = 256;
  constexpr int BK = 32;
  constexpr int ASZ = BM * BK;          // 4096 elems
  constexpr int SLOT = ASZ + BN * BK;   // 12288 elems = 24KB
  constexpr int L = 3;                  // loads per thread per tile (1 A + 2 B)
  constexpr int MF = 4;                 // m-frags per wave (128/2/16)

  extern __shared__ __align__(16) bf16 smem[];  // 3 * SLOT

  const int tid = threadIdx.x;

  // T1 XCD-chunked swizzle (nwg always a multiple of 8)
  const int gx = gridDim.x, gy = gridDim.y;
  const int nwg = gx * gy * gridDim.z;
  int id = (blockIdx.z * gy + blockIdx.y) * gx + blockIdx.x;
  id = (id & 7) * (nwg >> 3) + (id >> 3);
  const int bx = id % gx;
  const int t1 = id / gx;
  const int by = t1 % gy;
  const int bz = t1 / gy;

  const bf16* Ab = A  + (size_t)bz * bsA + (size_t)by * BM * K;
  const bf16* Bb = Bm + (size_t)bz * bsB + (size_t)bx * BN * K;

  const int lane = tid & 63;
  const int wid  = tid >> 6;
  const int l15 = lane & 15;
  const int lhi = lane >> 4;
  const int wr = (wid >> 2) * 64;
  const int wc = (wid & 3) * 64;

  // staging: thread -> (row = tid>>2, slot p = tid&3); LDS dst linear in lane.
  const int srow = tid >> 2;
  const int sp   = tid & 3;
  const int soct = (sp ^ ((srow >> 1) & 3)) << 3;
  const bf16* aSrc  = Ab + (size_t)srow * K + soct;
  const bf16* bSrc0 = Bb + (size_t)srow * K + soct;
  const bf16* bSrc1 = Bb + (size_t)(srow + 128) * K + soct;
  const int dstA = tid * 8;
  const int dstB0 = ASZ + tid * 8;
  const int dstB1 = ASZ + 4096 + tid * 8;

  const int koff = ((lhi ^ ((l15 >> 1) & 3)) << 3);

  f32x4 acc[MF][4];
  const f32x4 zero = {0.f, 0.f, 0.f, 0.f};
#pragma unroll
  for (int m = 0; m < MF; ++m)
#pragma unroll
    for (int n = 0; n < 4; ++n) acc[m][n] = zero;

  const int NT = K / BK;

  auto STAGE = [&](int t) {
    bf16* dst = smem + (size_t)(t % 3) * SLOT;
    const size_t kb = (size_t)t * BK;
    async_ld16(dst + dstA,  aSrc  + kb);
    async_ld16(dst + dstB0, bSrc0 + kb);
    async_ld16(dst + dstB1, bSrc1 + kb);
  };

  auto COMPUTE = [&](int t) {
    const bf16* buf = smem + (size_t)(t % 3) * SLOT;
    bf16x8 bf_[4];
#pragma unroll
    for (int n = 0; n < 4; ++n)
      bf_[n] = *(const bf16x8*)&buf[ASZ + (wc + n * 16 + l15) * BK + koff];
    __builtin_amdgcn_s_setprio(1);
#pragma unroll
    for (int m = 0; m < MF; ++m) {
      const bf16x8 af_ = *(const bf16x8*)&buf[(wr + m * 16 + l15) * BK + koff];
#pragma unroll
      for (int n = 0; n < 4; ++n)
        acc[m][n] = __builtin_amdgcn_mfma_f32_16x16x32_bf16(af_, bf_[n], acc[m][n], 0, 0, 0);
    }
    __builtin_amdgcn_s_setprio(0);
  };

  STAGE(0); STAGE(1);

  for (int t = 0; t < NT - 2; ++t) {
    STAGE(t + 2);
    wait_vmcnt<2 * L>();
    blk_barrier();
    COMPUTE(t);
    blk_barrier();
  }
  wait_vmcnt<L>(); blk_barrier(); COMPUTE(NT - 2); blk_barrier();
  wait_vmcnt<0>(); blk_barrier(); COMPUTE(NT - 1);

  // ---------------- epilogue: LDS-staged, coalesced ----------------
  __syncthreads();

  const int ccol_base = bx * BN + wc;
  const int wrow0 = by * BM + wr;

  float a2v = 0.f;
  if constexpr (EPI == EPI_DYT) a2v = al[0];

  if constexpr (EPI == EPI_PRIOR) {
    float* st = (float*)smem + wid * (32 * 68);
    const int lane4r = lane >> 4, lane16c = lane & 15;
    const int gcol = ccol_base + lane16c * 4;
    const bf16* prb = (const bf16*)prior;
#pragma unroll
    for (int mp = 0; mp < MF / 2; ++mp) {
#pragma unroll
      for (int mm = 0; mm < 2; ++mm) {
        const int m = mp * 2 + mm;
#pragma unroll
        for (int n = 0; n < 4; ++n) {
          const int col = ccol_base + n * 16 + l15;
          const float bcol = bias[col];
#pragma unroll
          for (int r = 0; r < 4; ++r) {
            const int lr = mm * 16 + (lhi << 2) + r;
            st[lr * 68 + n * 16 + l15] = acc[m][n][r] + bcol;
          }
        }
      }
      wait_lgkm0();
#pragma unroll
      for (int k = 0; k < 8; ++k) {
        const int lr = lane4r + 4 * k;
        f32x4 v = *(const f32x4*)&st[lr * 68 + lane16c * 4];
        const int grow = wrow0 + mp * 32 + lr;
        float* C = (float*)Cv + (size_t)bz * bsC;
        const bf16x4 p = *(const bf16x4*)&prb[(size_t)grow * 1024 + gcol];
        v[0] += (float)p[0]; v[1] += (float)p[1]; v[2] += (float)p[2]; v[3] += (float)p[3];
        *(f32x4*)&C[(size_t)grow * N + gcol] = v;
      }
      wait_lgkm0();
    }
  } else {
    bf16* st = (bf16*)smem + wid * (32 * 72);
    const int lane8r = lane >> 3, lane8c = lane & 7;
#pragma unroll
    for (int mp = 0; mp < MF / 2; ++mp) {
#pragma unroll
      for (int mm = 0; mm < 2; ++mm) {
        const int m = mp * 2 + mm;
        float mv[4];
        if constexpr (EPI == EPI_SCORES) {
#pragma unroll
          for (int r = 0; r < 4; ++r)
            mv[r] = al[(size_t)bz * 2048 + wrow0 + mp * 32 + mm * 16 + (lhi << 2) + r];
        }
        if constexpr (EPI == EPI_PV) {
#pragma unroll
          for (int r = 0; r < 4; ++r)
            mv[r] = 1.0f / al[(size_t)bz * 2048 + wrow0 + mp * 32 + mm * 16 + (lhi << 2) + r];
        }
#pragma unroll
        for (int n = 0; n < 4; ++n) {
          const int col = ccol_base + n * 16 + l15;
          float bcol = 0.f, wcol = 0.f, bvcol = 0.f;
          if constexpr (EPI == EPI_DYT) { bcol = bias[col]; wcol = wv[col]; bvcol = bv[col]; }
          if constexpr (EPI == EPI_GELU) bcol = bias[col];
#pragma unroll
          for (int r = 0; r < 4; ++r) {
            const int lr = mm * 16 + (lhi << 2) + r;
            const float v = acc[m][n][r];
            bf16 o;
            if constexpr (EPI == EPI_DYT) {
              o = (bf16)(tanhf(a2v * (v + bcol)) * wcol + bvcol);
            } else if constexpr (EPI == EPI_GELU) {
              const float g = v + bcol;
              o = (bf16)(0.5f * g * (1.0f + erff(g * 0.70710678118654752f)));
            } else if constexpr (EPI == EPI_SCORES) {
              const int row = wrow0 + mp * 32 + lr;
              o = (bf16)__expf(v * scale - fabsf((float)(row - col)) - mv[r]);
            } else if constexpr (EPI == EPI_PV) {
              o = (bf16)(v * mv[r]);
            } else {
              o = (bf16)v;
            }
            st[lr * 72 + n * 16 + l15] = o;
          }
        }
      }
      wait_lgkm0();
      if constexpr (EPI == EPI_QKV) {
        if (ccol_base >= 2048) {
          // V third: write TRANSPOSED to Vt[b][d][t] at (bf16*)Cv + 2*bsC.
          const int d = (ccol_base - 2048) + lane;
          const int grow0 = wrow0 + mp * 32;
          const int bb = grow0 >> 11;
          const int tt = grow0 & 2047;
          bf16* VT = (bf16*)Cv + 2ull * (size_t)bsC +
                     (size_t)bb * 2097152ull + (size_t)d * 2048 + tt;
#pragma unroll
          for (int tq = 0; tq < 4; ++tq) {
            bf16x8 w;
#pragma unroll
            for (int j = 0; j < 8; ++j) w[j] = st[(tq * 8 + j) * 72 + lane];
            *(bf16x8*)&VT[tq * 8] = w;
          }
        } else {
          bf16* C = (bf16*)Cv + (size_t)(ccol_base >> 10) * bsC;
#pragma unroll
          for (int k = 0; k < 4; ++k) {
            const int lr = lane8r + 8 * k;
            const bf16x8 v = *(const bf16x8*)&st[lr * 72 + lane8c * 8];
            const int grow = wrow0 + mp * 32 + lr;
            *(bf16x8*)&C[(size_t)grow * 1024 + (ccol_base & 1023) + lane8c * 8] = v;
          }
        }
      } else {
#pragma unroll
        for (int k = 0; k < 4; ++k) {
          const int lr = lane8r + 8 * k;
          const bf16x8 v = *(const bf16x8*)&st[lr * 72 + lane8c * 8];
          const int grow = wrow0 + mp * 32 + lr;
          bf16* C = (bf16*)Cv + (size_t)bz * bsC;
          *(bf16x8*)&C[(size_t)grow * N + ccol_base + lane8c * 8] = v;
          if constexpr (EPI == EPI_SCORES) {
            float s = 0.f;
#pragma unroll
            for (int j = 0; j < 8; ++j) s += (float)v[j];
            s += __shfl_xor(s, 1);
            s += __shfl_xor(s, 2);
            s += __shfl_xor(s, 4);
            if (lane8c == 0)
              atomicAdd(const_cast<float*>(bv) + (size_t)bz * 2048 + grow, s);
          }
        }
      }
      wait_lgkm0();
    }
  }
}

// ---------------------------------------------------------------------------
// reductions
// ---------------------------------------------------------------------------
DEVI float wave_red_sum(float v) {
#pragma unroll
  for (int o = 32; o > 0; o >>= 1) v += __shfl_xor(v, o);
  return v;
}
DEVI float wave_red_max(float v) {
#pragma unroll
  for (int o = 32; o > 0; o >>= 1) v = fmaxf(v, __shfl_xor(v, o));
  return v;
}
DEVI float block_red_max(float v, float* sm) {
  v = wave_red_max(v);
  if ((threadIdx.x & 63) == 0) sm[threadIdx.x >> 6] = v;
  __syncthreads();
  v = fmaxf(fmaxf(sm[0], sm[1]), fmaxf(sm[2], sm[3]));
  __syncthreads();
  return v;
}
DEVI float block_red_sum(float v, float* sm) {
  v = wave_red_sum(v);
  if ((threadIdx.x & 63) == 0) sm[threadIdx.x >> 6] = v;
  __syncthreads();
  v = sm[0] + sm[1] + sm[2] + sm[3];
  __syncthreads();
  return v;
}

// diag shift: m[row] = (Q_row . K_row) * scale; also zeroes rowsum[row]
__global__ __launch_bounds__(256) void diag_k(const bf16* __restrict__ Q,
                                              const bf16* __restrict__ K,
                                              float* __restrict__ m,
                                              float* __restrict__ rowsum, float scale) {
  const int row = blockIdx.x * 4 + (threadIdx.x >> 6);
  const int lane = threadIdx.x & 63;
  const bf16* q = Q + (size_t)row * 1024 + lane * 16;
  const bf16* k = K + (size_t)row * 1024 + lane * 16;
  float s = 0.f;
#pragma unroll
  for (int j = 0; j < 2; ++j) {
    const bf16x8 qv = *(const bf16x8*)(q + j * 8);
    const bf16x8 kv = *(const bf16x8*)(k + j * 8);
#pragma unroll
    for (int e = 0; e < 8; ++e) s += (float)qv[e] * (float)kv[e];
  }
  s = wave_red_sum(s);
  if (lane == 0) { m[row] = s * scale; rowsum[row] = 0.f; }
}

// ---------------------------------------------------------------------------
// fused: xpe = x + pos_embed; prior = dyt3(xpe) (BF16); xn = dyt1(xpe) (bf16)
// ---------------------------------------------------------------------------
__global__ __launch_bounds__(256) void ew_pre(
    const float* __restrict__ x, const float* __restrict__ pe,
    const float* __restrict__ a1p, const float* __restrict__ w1, const float* __restrict__ b1,
    const float* __restrict__ a3p, const float* __restrict__ w3, const float* __restrict__ b3,
    bf16* __restrict__ prior, bf16* __restrict__ xn, int total4)
{
  const float a1 = a1p[0], a3 = a3p[0];
  for (int i = blockIdx.x * 256 + threadIdx.x; i < total4; i += gridDim.x * 256) {
    const int dq = i & 255;
    const float4 xv  = ((const float4*)x)[i];
    const float4 pv  = ((const float4*)pe)[dq];
    const float4 w1v = ((const float4*)w1)[dq];
    const float4 b1v = ((const float4*)b1)[dq];
    const float4 w3v = ((const float4*)w3)[dq];
    const float4 b3v = ((const float4*)b3)[dq];
    const float x0 = xv.x + pv.x, x1 = xv.y + pv.y, x2 = xv.z + pv.z, x3 = xv.w + pv.w;
    bf16x4 prv;
    prv[0] = (bf16)(tanhf(a3 * x0) * w3v.x + b3v.x);
    prv[1] = (bf16)(tanhf(a3 * x1) * w3v.y + b3v.y);
    prv[2] = (bf16)(tanhf(a3 * x2) * w3v.z + b3v.z);
    prv[3] = (bf16)(tanhf(a3 * x3) * w3v.w + b3v.w);
    ((bf16x4*)prior)[i] = prv;
    bf16x4 o;
    o[0] = (bf16)(tanhf(a1 * x0) * w1v.x + b1v.x);
    o[1] = (bf16)(tanhf(a1 * x1) * w1v.y + b1v.y);
    o[2] = (bf16)(tanhf(a1 * x2) * w1v.z + b1v.z);
    o[3] = (bf16)(tanhf(a1 * x3) * w1v.w + b1v.w);
    ((bf16x4*)xn)[i] = o;
  }
}

// fp32 -> bf16 weight conversion, 6 segments via blockIdx.y
__global__ __launch_bounds__(256) void conv_w(
    const float* __restrict__ s0, const float* __restrict__ s1, const float* __restrict__ s2,
    const float* __restrict__ s3, const float* __restrict__ s4, const float* __restrict__ s5,
    bf16* __restrict__ d0, bf16* __restrict__ d1, bf16* __restrict__ d2,
    bf16* __restrict__ d3, bf16* __restrict__ d4, bf16* __restrict__ d5,
    int n0, int n1, int n2, int n3, int n4, int n5)
{
  const float* s; bf16* d; int n;
  switch (blockIdx.y) {
    case 0: s = s0; d = d0; n = n0; break;
    case 1: s = s1; d = d1; n = n1; break;
    case 2: s = s2; d = d2; n = n2; break;
    case 3: s = s3; d = d3; n = n3; break;
    case 4: s = s4; d = d4; n = n4; break;
    default: s = s5; d = d5; n = n5; break;
  }
  const int nq = n >> 2;
  for (int i = blockIdx.x * 256 + threadIdx.x; i < nq; i += gridDim.x * 256) {
    const float4 v = ((const float4*)s)[i];
    bf16x4 o;
    o[0] = (bf16)v.x; o[1] = (bf16)v.y; o[2] = (bf16)v.z; o[3] = (bf16)v.w;
    ((bf16x4*)d)[i] = o;
  }
}

// per-row JS pieces -> per-row partials (prior is bf16 now)
__global__ __launch_bounds__(256) void loss_k(const bf16* __restrict__ prior,
                                              const float* __restrict__ post,
                                              float* __restrict__ partial) {
  __shared__ float sm[4];
  const size_t row = blockIdx.x;
  const int t = threadIdx.x;
  const bf16x4 prb = *(const bf16x4*)&prior[row * 1024 + t * 4];
  const float4 po = *(const float4*)&post[row * 1024 + t * 4];
  float4 pr;
  pr.x = (float)prb[0]; pr.y = (float)prb[1]; pr.z = (float)prb[2]; pr.w = (float)prb[3];
  float4 mm;
  mm.x = 0.5f * (pr.x + po.x); mm.y = 0.5f * (pr.y + po.y);
  mm.z = 0.5f * (pr.z + po.z); mm.w = 0.5f * (pr.w + po.w);
  const float mxp = block_red_max(fmaxf(fmaxf(pr.x, pr.y), fmaxf(pr.z, pr.w)), sm);
  const float mxo = block_red_max(fmaxf(fmaxf(po.x, po.y), fmaxf(po.z, po.w)), sm);
  const float mxm = block_red_max(fmaxf(fmaxf(mm.x, mm.y), fmaxf(mm.z, mm.w)), sm);
  float sp = expf(pr.x - mxp) + expf(pr.y - mxp) + expf(pr.z - mxp) + expf(pr.w - mxp);
  sp = block_red_sum(sp, sm);
  float so = expf(po.x - mxo) + expf(po.y - mxo) + expf(po.z - mxo) + expf(po.w - mxo);
  so = block_red_sum(so, sm);
  const float em0 = expf(mm.x - mxm), em1 = expf(mm.y - mxm), em2 = expf(mm.z - mxm), em3 = expf(mm.w - mxm);
  float smm = block_red_sum(em0 + em1 + em2 + em3, sm);
  const float invm = 1.0f / smm;
  float s1 = em0 * invm * (mm.x - pr.x) + em1 * invm * (mm.y - pr.y) +
             em2 * invm * (mm.z - pr.z) + em3 * invm * (mm.w - pr.w);
  float s2 = em0 * invm * (mm.x - po.x) + em1 * invm * (mm.y - po.y) +
             em2 * invm * (mm.z - po.z) + em3 * invm * (mm.w - po.w);
  s1 = block_red_sum(s1, sm);
  s2 = block_red_sum(s2, sm);
  if (t == 0) {
    const float logZp = mxp + logf(sp);
    const float logZo = mxo + logf(so);
    const float logZm = mxm + logf(smm);
    partial[row]        = s1 + (logZp - logZm);
    partial[8192 + row] = s2 + (logZo - logZm);
  }
}

__global__ __launch_bounds__(1024) void loss_fin(const float* __restrict__ partial,
                                                 float* __restrict__ out) {
  __shared__ float sm[32];
  const int t = threadIdx.x;
  float a = 0.f, b = 0.f;
  for (int i = t; i < 8192; i += 1024) {
    a += partial[i];
    b += partial[8192 + i];
  }
  float v = a + b;
#pragma unroll
  for (int o = 32; o > 0; o >>= 1) v += __shfl_xor(v, o);
  if ((t & 63) == 0) sm[t >> 6] = v;
  __syncthreads();
  if (t == 0) {
    float s = 0.f;
#pragma unroll
    for (int w = 0; w < 16; ++w) s += sm[w];
    out[0] = 0.125f * s;
  }
}

// ---------------------------------------------------------------------------
extern "C" void kernel_launch(void* const* d_in, const int* in_sizes, int n_in,
                              void* d_out, int out_size, void* d_ws, size_t ws_size,
                              hipStream_t stream) {
  const float* x  = (const float*)d_in[0];
  const float* pe = (const float*)d_in[1];
  const float* a1 = (const float*)d_in[2];
  const float* w1 = (const float*)d_in[3];
  const float* b1 = (const float*)d_in[4];
  const float* a2 = (const float*)d_in[5];
  const float* w2 = (const float*)d_in[6];
  const float* b2 = (const float*)d_in[7];
  const float* a3 = (const float*)d_in[8];
  const float* w3 = (const float*)d_in[9];
  const float* b3 = (const float*)d_in[10];
  const float* Wq = (const float*)d_in[11];
  const float* Wk = (const float*)d_in[12];
  const float* Wv = (const float*)d_in[13];
  const float* Wp = (const float*)d_in[14];
  const float* bp = (const float*)d_in[15];
  const float* We = (const float*)d_in[16];
  const float* be = (const float*)d_in[17];
  const float* Wc = (const float*)d_in[18];
  const float* bc = (const float*)d_in[19];
  float* out = (float*)d_out;

  char* ws = (char*)d_ws;
  bf16*  prior  = (bf16*)(ws + 0);               // 16.8 MB bf16 (R12)
  bf16*  xn     = (bf16*)(ws + 33554432ull);     // reused: attn out
  bf16*  Qb     = (bf16*)(ws + 50331648ull);     // Q; K at +bsC; Vt at +2*bsC
  bf16*  Kb     = (bf16*)(ws + 67108864ull);
  bf16*  Vt     = (bf16*)(ws + 83886080ull);     // V TRANSPOSED [B][D][T]
  float* rowsum = (float*)(ws + 100663296ull);   // 32KB
  float* mvec   = (float*)(ws + 100728832ull);   // 32KB diag shift
  float* scores = (float*)(ws + 117440512ull);   // eb bf16 region, loss partials
  bf16*  Wqb    = (bf16*)(ws + 184549376ull);    // Wq/Wk/Wv contiguous
  bf16*  Wkb    = (bf16*)(ws + 186646528ull);
  bf16*  Wvb    = (bf16*)(ws + 188743680ull);
  bf16*  Wpb    = (bf16*)(ws + 190840832ull);
  bf16*  Web    = (bf16*)(ws + 192937984ull);
  bf16*  Wcb    = (bf16*)(ws + 201326592ull);
  bf16*  attno  = xn;
  bf16*  h2     = Qb;
  bf16*  eb     = (bf16*)scores;
  float* partial = (float*)(ws + 117440512ull);
  bf16*  probs  = (bf16*)d_out;  // unnormalized exp scores (bf16), consumed by PV

  static bool attr_done = false;
  if (!attr_done) {
    hipFuncSetAttribute((const void*)gemm2<EPI_QKV>,   hipFuncAttributeMaxDynamicSharedMemorySize, 73728);
    hipFuncSetAttribute((const void*)gemm2<EPI_SCORES>,hipFuncAttributeMaxDynamicSharedMemorySize, 73728);
    hipFuncSetAttribute((const void*)gemm2<EPI_PV>,    hipFuncAttributeMaxDynamicSharedMemorySize, 73728);
    hipFuncSetAttribute((const void*)gemm2<EPI_DYT>,   hipFuncAttributeMaxDynamicSharedMemorySize, 73728);
    hipFuncSetAttribute((const void*)gemm2<EPI_GELU>,  hipFuncAttributeMaxDynamicSharedMemorySize, 73728);
    hipFuncSetAttribute((const void*)gemm2<EPI_PRIOR>, hipFuncAttributeMaxDynamicSharedMemorySize, 73728);
    attr_done = true;
  }

  dim3 blk(256);
  dim3 gblk(512);
  constexpr unsigned SH = 73728;   // ring-3 * 24KB -> 2 blocks/CU

  conv_w<<<dim3(1024, 6), blk, 0, stream>>>(Wq, Wk, Wv, Wp, We, Wc,
                                            Wqb, Wkb, Wvb, Wpb, Web, Wcb,
                                            1048576, 1048576, 1048576, 1048576, 4194304, 4194304);
  ew_pre<<<2048, blk, 0, stream>>>(x, pe, a1, w1, b1, a3, w3, b3, prior, xn, 2097152);

  // fused QKV: [8192,3072] = xn @ [Wq;Wk;Wv]^T; V third written transposed
  gemm2<EPI_QKV><<<dim3(12, 64, 1), gblk, SH, stream>>>(xn, Wqb, Qb, 3072, 1024,
      0, 0, 8388608ll, nullptr, nullptr, nullptr, nullptr, nullptr, 0.f);

  // diag shift m[row] = (Q_row . K_row)/32 ; also zeroes rowsum
  diag_k<<<2048, blk, 0, stream>>>(Qb, Kb, mvec, rowsum, 0.03125f);

  // e[b,t,s] = exp((Q.K)/32 - |t-s| - m[t])  (bf16) + fp32 rowsum atomics
  gemm2<EPI_SCORES><<<dim3(8, 16, 4), gblk, SH, stream>>>(Qb, Kb, probs, 2048, 1024,
      2097152ll, 2097152ll, 4194304ll, nullptr, mvec, nullptr, rowsum, nullptr, 0.03125f);

  // out[b,t,d] = (e @ Vt) / rowsum[t]
  gemm2<EPI_PV><<<dim3(4, 16, 4), gblk, SH, stream>>>(probs, Vt, attno, 1024, 2048,
      4194304ll, 2097152ll, 2097152ll, nullptr, rowsum, nullptr, nullptr, nullptr, 0.f);

  // proj + dyt2
  gemm2<EPI_DYT><<<dim3(4, 64, 1), gblk, SH, stream>>>(attno, Wpb, h2, 1024, 1024,
      0, 0, 0, bp, a2, w2, b2, nullptr, 0.f);
  // expand + exact gelu
  gemm2<EPI_GELU><<<dim3(16, 64, 1), gblk, SH, stream>>>(h2, Web, eb, 4096, 1024,
      0, 0, 0, be, nullptr, nullptr, nullptr, nullptr, 0.f);
  // contract + bias + bf16 prior -> posterior (fp32)
  gemm2<EPI_PRIOR><<<dim3(4, 64, 1), gblk, SH, stream>>>(eb, Wcb, out, 1024, 4096,
      0, 0, 0, bc, nullptr, nullptr, nullptr, prior, 0.f);

  loss_k<<<8192, blk, 0, stream>>>(prior, out, partial);
  loss_fin<<<1, 1024, 0, stream>>>(partial, out + 8388608);
}

// Round 14
// 355.716 us; speedup vs baseline: 1.2083x; 1.1166x over previous
//
#include <hip/hip_runtime.h>
#include <cstdint>
#include <cstddef>

typedef __bf16 bf16;
typedef __bf16 bf16x4 __attribute__((ext_vector_type(4)));
typedef __bf16 bf16x8 __attribute__((ext_vector_type(8)));
typedef float  f32x4 __attribute__((ext_vector_type(4)));

#define DEVI __device__ __forceinline__

// ---------------------------------------------------------------------------
// async global->LDS (16B per lane)
// ---------------------------------------------------------------------------
DEVI void async_ld16(void* lds, const void* g) {
  const __attribute__((address_space(1))) uint32_t* g1 =
      reinterpret_cast<const __attribute__((address_space(1))) uint32_t*>(
          reinterpret_cast<uintptr_t>(g));
  uint32_t lo = (uint32_t)reinterpret_cast<uintptr_t>(lds);
  __attribute__((address_space(3))) uint32_t* l3 =
      reinterpret_cast<__attribute__((address_space(3))) uint32_t*>(lo);
  __builtin_amdgcn_global_load_lds(g1, l3, 16, 0, 0);
}

template <int N> DEVI void wait_vmcnt() {
  asm volatile("s_waitcnt vmcnt(%0)" :: "n"(N) : "memory");
}
DEVI void blk_barrier() {
  asm volatile("" ::: "memory");
  __builtin_amdgcn_s_barrier();
  asm volatile("" ::: "memory");
}
DEVI void wait_lgkm0() {
  asm volatile("s_waitcnt lgkmcnt(0)" ::: "memory");
}

enum { EPI_PV = 0, EPI_QKV = 1, EPI_SCORES = 2, EPI_DYT = 3, EPI_GELU = 4, EPI_PRIOR = 5 };

// ---------------------------------------------------------------------------
// B^T GEMM: C[row,col] = sum_k A[row,k]*B[col,k]   (R5 structure).
// BM=128, BN=256, BK=32, 8 waves, ring-3 LDS (72KB), 2 blocks/CU, counted
// vmcnt, raw barriers, setprio, XOR k-octet swizzle, coalesced epilogue.
// R10: EPI_QKV writes V third transposed (Vt at Cv + 2*bsC).
// R11: EPI_SCORES -> bf16 e = exp(score - m[row]) + fp32 rowsum atomics;
//      EPI_PV normalizes by 1/rowsum. R12: prior is bf16.
// R13: BANDED attention. |t-s|>=129 => e underflows bf16 to 0 (bias term
//      dominates), so blocks >=256 off-diagonal are skipped in SCORES
//      (grid bx'=0..2 maps to col-blocks cb0(by)..cb1(by); early-exit
//      prevents rowsum double-count) and PV's K-loop runs only over
//      [cb0*256,(cb1+1)*256) — exactly the region SCORES wrote.
//      Output is bit-identical to the full computation in bf16.
// ---------------------------------------------------------------------------
template <int EPI>
__global__ __launch_bounds__(512, 4) void gemm2(
    const bf16* __restrict__ A, const bf16* __restrict__ Bm, void* __restrict__ Cv,
    int N, int K,
    long long bsA, long long bsB, long long bsC,
    const float* __restrict__ bias, const float* __restrict__ al,
    const float* __restrict__ wv, const float* __restrict__ bv,
    const void* __restrict__ prior, float scale)
{
  constexpr int BM = 128;
  constexpr int BN = 256;
  constexpr int BK = 32;
  constexpr int ASZ = BM * BK;          // 4096 elems
  constexpr int SLOT = ASZ + BN * BK;   // 12288 elems = 24KB
  constexpr int L = 3;                  // loads per thread per tile (1 A + 2 B)
  constexpr int MF = 4;                 // m-frags per wave (128/2/16)

  extern __shared__ __align__(16) bf16 smem[];  // 3 * SLOT

  const int tid = threadIdx.x;

  // T1 XCD-chunked swizzle (nwg always a multiple of 8)
  const int gx = gridDim.x, gy = gridDim.y;
  const int nwg = gx * gy * gridDim.z;
  int id = (blockIdx.z * gy + blockIdx.y) * gx + blockIdx.x;
  id = (id & 7) * (nwg >> 3) + (id >> 3);
  int bx = id % gx;
  const int t1 = id / gx;
  const int by = t1 % gy;
  const int bz = t1 / gy;

  // R13: band windows (rows = by*128..+127; keep cols within +-256)
  int kt0 = 0, kt1 = K / BK;
  if constexpr (EPI == EPI_SCORES) {
    const int lo = by * 128 - 256;
    const int cb0 = (lo > 0 ? lo : 0) >> 8;
    const int hi = by * 128 + 383;
    const int cb1 = (hi < 2047 ? hi : 2047) >> 8;
    const int cb = cb0 + bx;
    if (cb > cb1) return;               // duplicate slot for 2-block rows
    bx = cb;
  }
  if constexpr (EPI == EPI_PV) {
    const int lo = by * 128 - 256;
    const int cb0 = (lo > 0 ? lo : 0) >> 8;
    const int hi = by * 128 + 383;
    const int cb1 = (hi < 2047 ? hi : 2047) >> 8;
    kt0 = cb0 * 8;                      // 256 cols = 8 K-tiles of 32
    kt1 = (cb1 + 1) * 8;
  }

  const bf16* Ab = A  + (size_t)bz * bsA + (size_t)by * BM * K;
  const bf16* Bb = Bm + (size_t)bz * bsB + (size_t)bx * BN * K;

  const int lane = tid & 63;
  const int wid  = tid >> 6;
  const int l15 = lane & 15;
  const int lhi = lane >> 4;
  const int wr = (wid >> 2) * 64;
  const int wc = (wid & 3) * 64;

  // staging: thread -> (row = tid>>2, slot p = tid&3); LDS dst linear in lane.
  const int srow = tid >> 2;
  const int sp   = tid & 3;
  const int soct = (sp ^ ((srow >> 1) & 3)) << 3;
  const bf16* aSrc  = Ab + (size_t)srow * K + soct;
  const bf16* bSrc0 = Bb + (size_t)srow * K + soct;
  const bf16* bSrc1 = Bb + (size_t)(srow + 128) * K + soct;
  const int dstA = tid * 8;
  const int dstB0 = ASZ + tid * 8;
  const int dstB1 = ASZ + 4096 + tid * 8;

  const int koff = ((lhi ^ ((l15 >> 1) & 3)) << 3);

  f32x4 acc[MF][4];
  const f32x4 zero = {0.f, 0.f, 0.f, 0.f};
#pragma unroll
  for (int m = 0; m < MF; ++m)
#pragma unroll
    for (int n = 0; n < 4; ++n) acc[m][n] = zero;

  auto STAGE = [&](int t) {
    bf16* dst = smem + (size_t)(t % 3) * SLOT;
    const size_t kb = (size_t)t * BK;
    async_ld16(dst + dstA,  aSrc  + kb);
    async_ld16(dst + dstB0, bSrc0 + kb);
    async_ld16(dst + dstB1, bSrc1 + kb);
  };

  auto COMPUTE = [&](int t) {
    const bf16* buf = smem + (size_t)(t % 3) * SLOT;
    bf16x8 bf_[4];
#pragma unroll
    for (int n = 0; n < 4; ++n)
      bf_[n] = *(const bf16x8*)&buf[ASZ + (wc + n * 16 + l15) * BK + koff];
    __builtin_amdgcn_s_setprio(1);
#pragma unroll
    for (int m = 0; m < MF; ++m) {
      const bf16x8 af_ = *(const bf16x8*)&buf[(wr + m * 16 + l15) * BK + koff];
#pragma unroll
      for (int n = 0; n < 4; ++n)
        acc[m][n] = __builtin_amdgcn_mfma_f32_16x16x32_bf16(af_, bf_[n], acc[m][n], 0, 0, 0);
    }
    __builtin_amdgcn_s_setprio(0);
  };

  STAGE(kt0); STAGE(kt0 + 1);

  for (int t = kt0; t < kt1 - 2; ++t) {
    STAGE(t + 2);
    wait_vmcnt<2 * L>();
    blk_barrier();
    COMPUTE(t);
    blk_barrier();
  }
  wait_vmcnt<L>(); blk_barrier(); COMPUTE(kt1 - 2); blk_barrier();
  wait_vmcnt<0>(); blk_barrier(); COMPUTE(kt1 - 1);

  // ---------------- epilogue: LDS-staged, coalesced ----------------
  __syncthreads();

  const int ccol_base = bx * BN + wc;
  const int wrow0 = by * BM + wr;

  float a2v = 0.f;
  if constexpr (EPI == EPI_DYT) a2v = al[0];

  if constexpr (EPI == EPI_PRIOR) {
    float* st = (float*)smem + wid * (32 * 68);
    const int lane4r = lane >> 4, lane16c = lane & 15;
    const int gcol = ccol_base + lane16c * 4;
    const bf16* prb = (const bf16*)prior;
#pragma unroll
    for (int mp = 0; mp < MF / 2; ++mp) {
#pragma unroll
      for (int mm = 0; mm < 2; ++mm) {
        const int m = mp * 2 + mm;
#pragma unroll
        for (int n = 0; n < 4; ++n) {
          const int col = ccol_base + n * 16 + l15;
          const float bcol = bias[col];
#pragma unroll
          for (int r = 0; r < 4; ++r) {
            const int lr = mm * 16 + (lhi << 2) + r;
            st[lr * 68 + n * 16 + l15] = acc[m][n][r] + bcol;
          }
        }
      }
      wait_lgkm0();
#pragma unroll
      for (int k = 0; k < 8; ++k) {
        const int lr = lane4r + 4 * k;
        f32x4 v = *(const f32x4*)&st[lr * 68 + lane16c * 4];
        const int grow = wrow0 + mp * 32 + lr;
        float* C = (float*)Cv + (size_t)bz * bsC;
        const bf16x4 p = *(const bf16x4*)&prb[(size_t)grow * 1024 + gcol];
        v[0] += (float)p[0]; v[1] += (float)p[1]; v[2] += (float)p[2]; v[3] += (float)p[3];
        *(f32x4*)&C[(size_t)grow * N + gcol] = v;
      }
      wait_lgkm0();
    }
  } else {
    bf16* st = (bf16*)smem + wid * (32 * 72);
    const int lane8r = lane >> 3, lane8c = lane & 7;
#pragma unroll
    for (int mp = 0; mp < MF / 2; ++mp) {
#pragma unroll
      for (int mm = 0; mm < 2; ++mm) {
        const int m = mp * 2 + mm;
        float mv[4];
        if constexpr (EPI == EPI_SCORES) {
#pragma unroll
          for (int r = 0; r < 4; ++r)
            mv[r] = al[(size_t)bz * 2048 + wrow0 + mp * 32 + mm * 16 + (lhi << 2) + r];
        }
        if constexpr (EPI == EPI_PV) {
#pragma unroll
          for (int r = 0; r < 4; ++r)
            mv[r] = 1.0f / al[(size_t)bz * 2048 + wrow0 + mp * 32 + mm * 16 + (lhi << 2) + r];
        }
#pragma unroll
        for (int n = 0; n < 4; ++n) {
          const int col = ccol_base + n * 16 + l15;
          float bcol = 0.f, wcol = 0.f, bvcol = 0.f;
          if constexpr (EPI == EPI_DYT) { bcol = bias[col]; wcol = wv[col]; bvcol = bv[col]; }
          if constexpr (EPI == EPI_GELU) bcol = bias[col];
#pragma unroll
          for (int r = 0; r < 4; ++r) {
            const int lr = mm * 16 + (lhi << 2) + r;
            const float v = acc[m][n][r];
            bf16 o;
            if constexpr (EPI == EPI_DYT) {
              o = (bf16)(tanhf(a2v * (v + bcol)) * wcol + bvcol);
            } else if constexpr (EPI == EPI_GELU) {
              const float g = v + bcol;
              o = (bf16)(0.5f * g * (1.0f + erff(g * 0.70710678118654752f)));
            } else if constexpr (EPI == EPI_SCORES) {
              const int row = wrow0 + mp * 32 + lr;
              o = (bf16)__expf(v * scale - fabsf((float)(row - col)) - mv[r]);
            } else if constexpr (EPI == EPI_PV) {
              o = (bf16)(v * mv[r]);
            } else {
              o = (bf16)v;
            }
            st[lr * 72 + n * 16 + l15] = o;
          }
        }
      }
      wait_lgkm0();
      if constexpr (EPI == EPI_QKV) {
        if (ccol_base >= 2048) {
          // V third: write TRANSPOSED to Vt[b][d][t] at (bf16*)Cv + 2*bsC.
          const int d = (ccol_base - 2048) + lane;
          const int grow0 = wrow0 + mp * 32;
          const int bb = grow0 >> 11;
          const int tt = grow0 & 2047;
          bf16* VT = (bf16*)Cv + 2ull * (size_t)bsC +
                     (size_t)bb * 2097152ull + (size_t)d * 2048 + tt;
#pragma unroll
          for (int tq = 0; tq < 4; ++tq) {
            bf16x8 w;
#pragma unroll
            for (int j = 0; j < 8; ++j) w[j] = st[(tq * 8 + j) * 72 + lane];
            *(bf16x8*)&VT[tq * 8] = w;
          }
        } else {
          bf16* C = (bf16*)Cv + (size_t)(ccol_base >> 10) * bsC;
#pragma unroll
          for (int k = 0; k < 4; ++k) {
            const int lr = lane8r + 8 * k;
            const bf16x8 v = *(const bf16x8*)&st[lr * 72 + lane8c * 8];
            const int grow = wrow0 + mp * 32 + lr;
            *(bf16x8*)&C[(size_t)grow * 1024 + (ccol_base & 1023) + lane8c * 8] = v;
          }
        }
      } else {
#pragma unroll
        for (int k = 0; k < 4; ++k) {
          const int lr = lane8r + 8 * k;
          const bf16x8 v = *(const bf16x8*)&st[lr * 72 + lane8c * 8];
          const int grow = wrow0 + mp * 32 + lr;
          bf16* C = (bf16*)Cv + (size_t)bz * bsC;
          *(bf16x8*)&C[(size_t)grow * N + ccol_base + lane8c * 8] = v;
          if constexpr (EPI == EPI_SCORES) {
            float s = 0.f;
#pragma unroll
            for (int j = 0; j < 8; ++j) s += (float)v[j];
            s += __shfl_xor(s, 1);
            s += __shfl_xor(s, 2);
            s += __shfl_xor(s, 4);
            if (lane8c == 0)
              atomicAdd(const_cast<float*>(bv) + (size_t)bz * 2048 + grow, s);
          }
        }
      }
      wait_lgkm0();
    }
  }
}

// ---------------------------------------------------------------------------
// reductions
// ---------------------------------------------------------------------------
DEVI float wave_red_sum(float v) {
#pragma unroll
  for (int o = 32; o > 0; o >>= 1) v += __shfl_xor(v, o);
  return v;
}
DEVI float wave_red_max(float v) {
#pragma unroll
  for (int o = 32; o > 0; o >>= 1) v = fmaxf(v, __shfl_xor(v, o));
  return v;
}
DEVI float block_red_max(float v, float* sm) {
  v = wave_red_max(v);
  if ((threadIdx.x & 63) == 0) sm[threadIdx.x >> 6] = v;
  __syncthreads();
  v = fmaxf(fmaxf(sm[0], sm[1]), fmaxf(sm[2], sm[3]));
  __syncthreads();
  return v;
}
DEVI float block_red_sum(float v, float* sm) {
  v = wave_red_sum(v);
  if ((threadIdx.x & 63) == 0) sm[threadIdx.x >> 6] = v;
  __syncthreads();
  v = sm[0] + sm[1] + sm[2] + sm[3];
  __syncthreads();
  return v;
}

// diag shift: m[row] = (Q_row . K_row) * scale; also zeroes rowsum[row]
__global__ __launch_bounds__(256) void diag_k(const bf16* __restrict__ Q,
                                              const bf16* __restrict__ K,
                                              float* __restrict__ m,
                                              float* __restrict__ rowsum, float scale) {
  const int row = blockIdx.x * 4 + (threadIdx.x >> 6);
  const int lane = threadIdx.x & 63;
  const bf16* q = Q + (size_t)row * 1024 + lane * 16;
  const bf16* k = K + (size_t)row * 1024 + lane * 16;
  float s = 0.f;
#pragma unroll
  for (int j = 0; j < 2; ++j) {
    const bf16x8 qv = *(const bf16x8*)(q + j * 8);
    const bf16x8 kv = *(const bf16x8*)(k + j * 8);
#pragma unroll
    for (int e = 0; e < 8; ++e) s += (float)qv[e] * (float)kv[e];
  }
  s = wave_red_sum(s);
  if (lane == 0) { m[row] = s * scale; rowsum[row] = 0.f; }
}

// ---------------------------------------------------------------------------
// fused: xpe = x + pos_embed; prior = dyt3(xpe) (BF16); xn = dyt1(xpe) (bf16)
// ---------------------------------------------------------------------------
__global__ __launch_bounds__(256) void ew_pre(
    const float* __restrict__ x, const float* __restrict__ pe,
    const float* __restrict__ a1p, const float* __restrict__ w1, const float* __restrict__ b1,
    const float* __restrict__ a3p, const float* __restrict__ w3, const float* __restrict__ b3,
    bf16* __restrict__ prior, bf16* __restrict__ xn, int total4)
{
  const float a1 = a1p[0], a3 = a3p[0];
  for (int i = blockIdx.x * 256 + threadIdx.x; i < total4; i += gridDim.x * 256) {
    const int dq = i & 255;
    const float4 xv  = ((const float4*)x)[i];
    const float4 pv  = ((const float4*)pe)[dq];
    const float4 w1v = ((const float4*)w1)[dq];
    const float4 b1v = ((const float4*)b1)[dq];
    const float4 w3v = ((const float4*)w3)[dq];
    const float4 b3v = ((const float4*)b3)[dq];
    const float x0 = xv.x + pv.x, x1 = xv.y + pv.y, x2 = xv.z + pv.z, x3 = xv.w + pv.w;
    bf16x4 prv;
    prv[0] = (bf16)(tanhf(a3 * x0) * w3v.x + b3v.x);
    prv[1] = (bf16)(tanhf(a3 * x1) * w3v.y + b3v.y);
    prv[2] = (bf16)(tanhf(a3 * x2) * w3v.z + b3v.z);
    prv[3] = (bf16)(tanhf(a3 * x3) * w3v.w + b3v.w);
    ((bf16x4*)prior)[i] = prv;
    bf16x4 o;
    o[0] = (bf16)(tanhf(a1 * x0) * w1v.x + b1v.x);
    o[1] = (bf16)(tanhf(a1 * x1) * w1v.y + b1v.y);
    o[2] = (bf16)(tanhf(a1 * x2) * w1v.z + b1v.z);
    o[3] = (bf16)(tanhf(a1 * x3) * w1v.w + b1v.w);
    ((bf16x4*)xn)[i] = o;
  }
}

// fp32 -> bf16 weight conversion, 6 segments via blockIdx.y
__global__ __launch_bounds__(256) void conv_w(
    const float* __restrict__ s0, const float* __restrict__ s1, const float* __restrict__ s2,
    const float* __restrict__ s3, const float* __restrict__ s4, const float* __restrict__ s5,
    bf16* __restrict__ d0, bf16* __restrict__ d1, bf16* __restrict__ d2,
    bf16* __restrict__ d3, bf16* __restrict__ d4, bf16* __restrict__ d5,
    int n0, int n1, int n2, int n3, int n4, int n5)
{
  const float* s; bf16* d; int n;
  switch (blockIdx.y) {
    case 0: s = s0; d = d0; n = n0; break;
    case 1: s = s1; d = d1; n = n1; break;
    case 2: s = s2; d = d2; n = n2; break;
    case 3: s = s3; d = d3; n = n3; break;
    case 4: s = s4; d = d4; n = n4; break;
    default: s = s5; d = d5; n = n5; break;
  }
  const int nq = n >> 2;
  for (int i = blockIdx.x * 256 + threadIdx.x; i < nq; i += gridDim.x * 256) {
    const float4 v = ((const float4*)s)[i];
    bf16x4 o;
    o[0] = (bf16)v.x; o[1] = (bf16)v.y; o[2] = (bf16)v.z; o[3] = (bf16)v.w;
    ((bf16x4*)d)[i] = o;
  }
}

// per-row JS pieces -> per-row partials (prior is bf16)
__global__ __launch_bounds__(256) void loss_k(const bf16* __restrict__ prior,
                                              const float* __restrict__ post,
                                              float* __restrict__ partial) {
  __shared__ float sm[4];
  const size_t row = blockIdx.x;
  const int t = threadIdx.x;
  const bf16x4 prb = *(const bf16x4*)&prior[row * 1024 + t * 4];
  const float4 po = *(const float4*)&post[row * 1024 + t * 4];
  float4 pr;
  pr.x = (float)prb[0]; pr.y = (float)prb[1]; pr.z = (float)prb[2]; pr.w = (float)prb[3];
  float4 mm;
  mm.x = 0.5f * (pr.x + po.x); mm.y = 0.5f * (pr.y + po.y);
  mm.z = 0.5f * (pr.z + po.z); mm.w = 0.5f * (pr.w + po.w);
  const float mxp = block_red_max(fmaxf(fmaxf(pr.x, pr.y), fmaxf(pr.z, pr.w)), sm);
  const float mxo = block_red_max(fmaxf(fmaxf(po.x, po.y), fmaxf(po.z, po.w)), sm);
  const float mxm = block_red_max(fmaxf(fmaxf(mm.x, mm.y), fmaxf(mm.z, mm.w)), sm);
  float sp = expf(pr.x - mxp) + expf(pr.y - mxp) + expf(pr.z - mxp) + expf(pr.w - mxp);
  sp = block_red_sum(sp, sm);
  float so = expf(po.x - mxo) + expf(po.y - mxo) + expf(po.z - mxo) + expf(po.w - mxo);
  so = block_red_sum(so, sm);
  const float em0 = expf(mm.x - mxm), em1 = expf(mm.y - mxm), em2 = expf(mm.z - mxm), em3 = expf(mm.w - mxm);
  float smm = block_red_sum(em0 + em1 + em2 + em3, sm);
  const float invm = 1.0f / smm;
  float s1 = em0 * invm * (mm.x - pr.x) + em1 * invm * (mm.y - pr.y) +
             em2 * invm * (mm.z - pr.z) + em3 * invm * (mm.w - pr.w);
  float s2 = em0 * invm * (mm.x - po.x) + em1 * invm * (mm.y - po.y) +
             em2 * invm * (mm.z - po.z) + em3 * invm * (mm.w - po.w);
  s1 = block_red_sum(s1, sm);
  s2 = block_red_sum(s2, sm);
  if (t == 0) {
    const float logZp = mxp + logf(sp);
    const float logZo = mxo + logf(so);
    const float logZm = mxm + logf(smm);
    partial[row]        = s1 + (logZp - logZm);
    partial[8192 + row] = s2 + (logZo - logZm);
  }
}

__global__ __launch_bounds__(1024) void loss_fin(const float* __restrict__ partial,
                                                 float* __restrict__ out) {
  __shared__ float sm[32];
  const int t = threadIdx.x;
  float a = 0.f, b = 0.f;
  for (int i = t; i < 8192; i += 1024) {
    a += partial[i];
    b += partial[8192 + i];
  }
  float v = a + b;
#pragma unroll
  for (int o = 32; o > 0; o >>= 1) v += __shfl_xor(v, o);
  if ((t & 63) == 0) sm[t >> 6] = v;
  __syncthreads();
  if (t == 0) {
    float s = 0.f;
#pragma unroll
    for (int w = 0; w < 16; ++w) s += sm[w];
    out[0] = 0.125f * s;
  }
}

// ---------------------------------------------------------------------------
extern "C" void kernel_launch(void* const* d_in, const int* in_sizes, int n_in,
                              void* d_out, int out_size, void* d_ws, size_t ws_size,
                              hipStream_t stream) {
  const float* x  = (const float*)d_in[0];
  const float* pe = (const float*)d_in[1];
  const float* a1 = (const float*)d_in[2];
  const float* w1 = (const float*)d_in[3];
  const float* b1 = (const float*)d_in[4];
  const float* a2 = (const float*)d_in[5];
  const float* w2 = (const float*)d_in[6];
  const float* b2 = (const float*)d_in[7];
  const float* a3 = (const float*)d_in[8];
  const float* w3 = (const float*)d_in[9];
  const float* b3 = (const float*)d_in[10];
  const float* Wq = (const float*)d_in[11];
  const float* Wk = (const float*)d_in[12];
  const float* Wv = (const float*)d_in[13];
  const float* Wp = (const float*)d_in[14];
  const float* bp = (const float*)d_in[15];
  const float* We = (const float*)d_in[16];
  const float* be = (const float*)d_in[17];
  const float* Wc = (const float*)d_in[18];
  const float* bc = (const float*)d_in[19];
  float* out = (float*)d_out;

  char* ws = (char*)d_ws;
  bf16*  prior  = (bf16*)(ws + 0);               // 16.8 MB bf16
  bf16*  xn     = (bf16*)(ws + 33554432ull);     // reused: attn out
  bf16*  Qb     = (bf16*)(ws + 50331648ull);     // Q; K at +bsC; Vt at +2*bsC
  bf16*  Kb     = (bf16*)(ws + 67108864ull);
  bf16*  Vt     = (bf16*)(ws + 83886080ull);     // V TRANSPOSED [B][D][T]
  float* rowsum = (float*)(ws + 100663296ull);   // 32KB
  float* mvec   = (float*)(ws + 100728832ull);   // 32KB diag shift
  float* scores = (float*)(ws + 117440512ull);   // eb bf16 region, loss partials
  bf16*  Wqb    = (bf16*)(ws + 184549376ull);    // Wq/Wk/Wv contiguous
  bf16*  Wkb    = (bf16*)(ws + 186646528ull);
  bf16*  Wvb    = (bf16*)(ws + 188743680ull);
  bf16*  Wpb    = (bf16*)(ws + 190840832ull);
  bf16*  Web    = (bf16*)(ws + 192937984ull);
  bf16*  Wcb    = (bf16*)(ws + 201326592ull);
  bf16*  attno  = xn;
  bf16*  h2     = Qb;
  bf16*  eb     = (bf16*)scores;
  float* partial = (float*)(ws + 117440512ull);
  bf16*  probs  = (bf16*)d_out;  // unnormalized exp scores (bf16), banded

  static bool attr_done = false;
  if (!attr_done) {
    hipFuncSetAttribute((const void*)gemm2<EPI_QKV>,   hipFuncAttributeMaxDynamicSharedMemorySize, 73728);
    hipFuncSetAttribute((const void*)gemm2<EPI_SCORES>,hipFuncAttributeMaxDynamicSharedMemorySize, 73728);
    hipFuncSetAttribute((const void*)gemm2<EPI_PV>,    hipFuncAttributeMaxDynamicSharedMemorySize, 73728);
    hipFuncSetAttribute((const void*)gemm2<EPI_DYT>,   hipFuncAttributeMaxDynamicSharedMemorySize, 73728);
    hipFuncSetAttribute((const void*)gemm2<EPI_GELU>,  hipFuncAttributeMaxDynamicSharedMemorySize, 73728);
    hipFuncSetAttribute((const void*)gemm2<EPI_PRIOR>, hipFuncAttributeMaxDynamicSharedMemorySize, 73728);
    attr_done = true;
  }

  dim3 blk(256);
  dim3 gblk(512);
  constexpr unsigned SH = 73728;   // ring-3 * 24KB -> 2 blocks/CU

  conv_w<<<dim3(1024, 6), blk, 0, stream>>>(Wq, Wk, Wv, Wp, We, Wc,
                                            Wqb, Wkb, Wvb, Wpb, Web, Wcb,
                                            1048576, 1048576, 1048576, 1048576, 4194304, 4194304);
  ew_pre<<<2048, blk, 0, stream>>>(x, pe, a1, w1, b1, a3, w3, b3, prior, xn, 2097152);

  // fused QKV: [8192,3072] = xn @ [Wq;Wk;Wv]^T; V third written transposed
  gemm2<EPI_QKV><<<dim3(12, 64, 1), gblk, SH, stream>>>(xn, Wqb, Qb, 3072, 1024,
      0, 0, 8388608ll, nullptr, nullptr, nullptr, nullptr, nullptr, 0.f);

  // diag shift m[row] = (Q_row . K_row)/32 ; also zeroes rowsum
  diag_k<<<2048, blk, 0, stream>>>(Qb, Kb, mvec, rowsum, 0.03125f);

  // BANDED e[b,t,s] = exp((Q.K)/32 - |t-s| - m[t]) (bf16) + rowsum atomics.
  // bx'=0..2 -> col-blocks cb0(by)..cb1(by); off-band blocks are bf16-zero.
  gemm2<EPI_SCORES><<<dim3(3, 16, 4), gblk, SH, stream>>>(Qb, Kb, probs, 2048, 1024,
      2097152ll, 2097152ll, 4194304ll, nullptr, mvec, nullptr, rowsum, nullptr, 0.03125f);

  // BANDED out[b,t,d] = (e @ Vt) / rowsum[t]  (K-loop over written window)
  gemm2<EPI_PV><<<dim3(4, 16, 4), gblk, SH, stream>>>(probs, Vt, attno, 1024, 2048,
      4194304ll, 2097152ll, 2097152ll, nullptr, rowsum, nullptr, nullptr, nullptr, 0.f);

  // proj + dyt2
  gemm2<EPI_DYT><<<dim3(4, 64, 1), gblk, SH, stream>>>(attno, Wpb, h2, 1024, 1024,
      0, 0, 0, bp, a2, w2, b2, nullptr, 0.f);
  // expand + exact gelu
  gemm2<EPI_GELU><<<dim3(16, 64, 1), gblk, SH, stream>>>(h2, Web, eb, 4096, 1024,
      0, 0, 0, be, nullptr, nullptr, nullptr, nullptr, 0.f);
  // contract + bias + bf16 prior -> posterior (fp32)
  gemm2<EPI_PRIOR><<<dim3(4, 64, 1), gblk, SH, stream>>>(eb, Wcb, out, 1024, 4096,
      0, 0, 0, bc, nullptr, nullptr, nullptr, prior, 0.f);

  loss_k<<<8192, blk, 0, stream>>>(prior, out, partial);
  loss_fin<<<1, 1024, 0, stream>>>(partial, out + 8388608);
}

// Round 15
// 351.416 us; speedup vs baseline: 1.2231x; 1.0122x over previous
//
#include <hip/hip_runtime.h>
#include <cstdint>
#include <cstddef>

typedef __bf16 bf16;
typedef __bf16 bf16x4 __attribute__((ext_vector_type(4)));
typedef __bf16 bf16x8 __attribute__((ext_vector_type(8)));
typedef float  f32x4 __attribute__((ext_vector_type(4)));

#define DEVI __device__ __forceinline__

// ---------------------------------------------------------------------------
// async global->LDS (16B per lane)
// ---------------------------------------------------------------------------
DEVI void async_ld16(void* lds, const void* g) {
  const __attribute__((address_space(1))) uint32_t* g1 =
      reinterpret_cast<const __attribute__((address_space(1))) uint32_t*>(
          reinterpret_cast<uintptr_t>(g));
  uint32_t lo = (uint32_t)reinterpret_cast<uintptr_t>(lds);
  __attribute__((address_space(3))) uint32_t* l3 =
      reinterpret_cast<__attribute__((address_space(3))) uint32_t*>(lo);
  __builtin_amdgcn_global_load_lds(g1, l3, 16, 0, 0);
}

template <int N> DEVI void wait_vmcnt() {
  asm volatile("s_waitcnt vmcnt(%0)" :: "n"(N) : "memory");
}
DEVI void blk_barrier() {
  asm volatile("" ::: "memory");
  __builtin_amdgcn_s_barrier();
  asm volatile("" ::: "memory");
}
DEVI void wait_lgkm0() {
  asm volatile("s_waitcnt lgkmcnt(0)" ::: "memory");
}

enum { EPI_PV = 0, EPI_QKV = 1, EPI_SCORES = 2, EPI_DYT = 3, EPI_GELU = 4, EPI_PRIOR = 5 };

// ---------------------------------------------------------------------------
// B^T GEMM: C[row,col] = sum_k A[row,k]*B[col,k]   (R5 structure).
// BM=128, BN=256, BK=32, 8 waves, ring-3 LDS (72KB), 2 blocks/CU, counted
// vmcnt, raw barriers, setprio, XOR k-octet swizzle, coalesced epilogue.
// R10: EPI_QKV writes V third transposed (Vt at Cv + 2*bsC).
// R11: EPI_SCORES -> bf16 e = exp(score - m[row]) + fp32 rowsum atomics;
//      EPI_PV normalizes by 1/rowsum. R12: prior is bf16.
// R13/R14: BANDED attention, minimal window. Keep cols [t0-128, t0+255]
//      per 128-row block (<=2 col-blocks after 256-alignment). All dropped
//      entries have |t-s| >= 129 -> e < 3e-56 -> bf16 EXACT zero, so the
//      banded result is bit-identical to the full computation.
// ---------------------------------------------------------------------------
template <int EPI>
__global__ __launch_bounds__(512, 4) void gemm2(
    const bf16* __restrict__ A, const bf16* __restrict__ Bm, void* __restrict__ Cv,
    int N, int K,
    long long bsA, long long bsB, long long bsC,
    const float* __restrict__ bias, const float* __restrict__ al,
    const float* __restrict__ wv, const float* __restrict__ bv,
    const void* __restrict__ prior, float scale)
{
  constexpr int BM = 128;
  constexpr int BN = 256;
  constexpr int BK = 32;
  constexpr int ASZ = BM * BK;          // 4096 elems
  constexpr int SLOT = ASZ + BN * BK;   // 12288 elems = 24KB
  constexpr int L = 3;                  // loads per thread per tile (1 A + 2 B)
  constexpr int MF = 4;                 // m-frags per wave (128/2/16)

  extern __shared__ __align__(16) bf16 smem[];  // 3 * SLOT

  const int tid = threadIdx.x;

  // T1 XCD-chunked swizzle (nwg always a multiple of 8)
  const int gx = gridDim.x, gy = gridDim.y;
  const int nwg = gx * gy * gridDim.z;
  int id = (blockIdx.z * gy + blockIdx.y) * gx + blockIdx.x;
  id = (id & 7) * (nwg >> 3) + (id >> 3);
  int bx = id % gx;
  const int t1 = id / gx;
  const int by = t1 % gy;
  const int bz = t1 / gy;

  // R14: minimal band windows (rows t0..t0+127; keep cols [t0-128, t0+255])
  int kt0 = 0, kt1 = K / BK;
  if constexpr (EPI == EPI_SCORES) {
    const int lo = by * 128 - 128;
    const int cb0 = (lo > 0 ? lo : 0) >> 8;
    const int hi0 = by * 128 + 255;
    const int cb1 = (hi0 < 2047 ? hi0 : 2047) >> 8;
    const int cb = cb0 + bx;
    if (cb > cb1) return;               // by=0 / by=15 have 1 block
    bx = cb;
  }
  if constexpr (EPI == EPI_PV) {
    const int lo = by * 128 - 128;
    const int cb0 = (lo > 0 ? lo : 0) >> 8;
    const int hi0 = by * 128 + 255;
    const int cb1 = (hi0 < 2047 ? hi0 : 2047) >> 8;
    kt0 = cb0 * 8;                      // 256 cols = 8 K-tiles of 32
    kt1 = (cb1 + 1) * 8;
  }

  const bf16* Ab = A  + (size_t)bz * bsA + (size_t)by * BM * K;
  const bf16* Bb = Bm + (size_t)bz * bsB + (size_t)bx * BN * K;

  const int lane = tid & 63;
  const int wid  = tid >> 6;
  const int l15 = lane & 15;
  const int lhi = lane >> 4;
  const int wr = (wid >> 2) * 64;
  const int wc = (wid & 3) * 64;

  // staging: thread -> (row = tid>>2, slot p = tid&3); LDS dst linear in lane.
  const int srow = tid >> 2;
  const int sp   = tid & 3;
  const int soct = (sp ^ ((srow >> 1) & 3)) << 3;
  const bf16* aSrc  = Ab + (size_t)srow * K + soct;
  const bf16* bSrc0 = Bb + (size_t)srow * K + soct;
  const bf16* bSrc1 = Bb + (size_t)(srow + 128) * K + soct;
  const int dstA = tid * 8;
  const int dstB0 = ASZ + tid * 8;
  const int dstB1 = ASZ + 4096 + tid * 8;

  const int koff = ((lhi ^ ((l15 >> 1) & 3)) << 3);

  f32x4 acc[MF][4];
  const f32x4 zero = {0.f, 0.f, 0.f, 0.f};
#pragma unroll
  for (int m = 0; m < MF; ++m)
#pragma unroll
    for (int n = 0; n < 4; ++n) acc[m][n] = zero;

  auto STAGE = [&](int t) {
    bf16* dst = smem + (size_t)(t % 3) * SLOT;
    const size_t kb = (size_t)t * BK;
    async_ld16(dst + dstA,  aSrc  + kb);
    async_ld16(dst + dstB0, bSrc0 + kb);
    async_ld16(dst + dstB1, bSrc1 + kb);
  };

  auto COMPUTE = [&](int t) {
    const bf16* buf = smem + (size_t)(t % 3) * SLOT;
    bf16x8 bf_[4];
#pragma unroll
    for (int n = 0; n < 4; ++n)
      bf_[n] = *(const bf16x8*)&buf[ASZ + (wc + n * 16 + l15) * BK + koff];
    __builtin_amdgcn_s_setprio(1);
#pragma unroll
    for (int m = 0; m < MF; ++m) {
      const bf16x8 af_ = *(const bf16x8*)&buf[(wr + m * 16 + l15) * BK + koff];
#pragma unroll
      for (int n = 0; n < 4; ++n)
        acc[m][n] = __builtin_amdgcn_mfma_f32_16x16x32_bf16(af_, bf_[n], acc[m][n], 0, 0, 0);
    }
    __builtin_amdgcn_s_setprio(0);
  };

  STAGE(kt0); STAGE(kt0 + 1);

  for (int t = kt0; t < kt1 - 2; ++t) {
    STAGE(t + 2);
    wait_vmcnt<2 * L>();
    blk_barrier();
    COMPUTE(t);
    blk_barrier();
  }
  wait_vmcnt<L>(); blk_barrier(); COMPUTE(kt1 - 2); blk_barrier();
  wait_vmcnt<0>(); blk_barrier(); COMPUTE(kt1 - 1);

  // ---------------- epilogue: LDS-staged, coalesced ----------------
  __syncthreads();

  const int ccol_base = bx * BN + wc;
  const int wrow0 = by * BM + wr;

  float a2v = 0.f;
  if constexpr (EPI == EPI_DYT) a2v = al[0];

  if constexpr (EPI == EPI_PRIOR) {
    float* st = (float*)smem + wid * (32 * 68);
    const int lane4r = lane >> 4, lane16c = lane & 15;
    const int gcol = ccol_base + lane16c * 4;
    const bf16* prb = (const bf16*)prior;
#pragma unroll
    for (int mp = 0; mp < MF / 2; ++mp) {
#pragma unroll
      for (int mm = 0; mm < 2; ++mm) {
        const int m = mp * 2 + mm;
#pragma unroll
        for (int n = 0; n < 4; ++n) {
          const int col = ccol_base + n * 16 + l15;
          const float bcol = bias[col];
#pragma unroll
          for (int r = 0; r < 4; ++r) {
            const int lr = mm * 16 + (lhi << 2) + r;
            st[lr * 68 + n * 16 + l15] = acc[m][n][r] + bcol;
          }
        }
      }
      wait_lgkm0();
#pragma unroll
      for (int k = 0; k < 8; ++k) {
        const int lr = lane4r + 4 * k;
        f32x4 v = *(const f32x4*)&st[lr * 68 + lane16c * 4];
        const int grow = wrow0 + mp * 32 + lr;
        float* C = (float*)Cv + (size_t)bz * bsC;
        const bf16x4 p = *(const bf16x4*)&prb[(size_t)grow * 1024 + gcol];
        v[0] += (float)p[0]; v[1] += (float)p[1]; v[2] += (float)p[2]; v[3] += (float)p[3];
        *(f32x4*)&C[(size_t)grow * N + gcol] = v;
      }
      wait_lgkm0();
    }
  } else {
    bf16* st = (bf16*)smem + wid * (32 * 72);
    const int lane8r = lane >> 3, lane8c = lane & 7;
#pragma unroll
    for (int mp = 0; mp < MF / 2; ++mp) {
#pragma unroll
      for (int mm = 0; mm < 2; ++mm) {
        const int m = mp * 2 + mm;
        float mv[4];
        if constexpr (EPI == EPI_SCORES) {
#pragma unroll
          for (int r = 0; r < 4; ++r)
            mv[r] = al[(size_t)bz * 2048 + wrow0 + mp * 32 + mm * 16 + (lhi << 2) + r];
        }
        if constexpr (EPI == EPI_PV) {
#pragma unroll
          for (int r = 0; r < 4; ++r)
            mv[r] = 1.0f / al[(size_t)bz * 2048 + wrow0 + mp * 32 + mm * 16 + (lhi << 2) + r];
        }
#pragma unroll
        for (int n = 0; n < 4; ++n) {
          const int col = ccol_base + n * 16 + l15;
          float bcol = 0.f, wcol = 0.f, bvcol = 0.f;
          if constexpr (EPI == EPI_DYT) { bcol = bias[col]; wcol = wv[col]; bvcol = bv[col]; }
          if constexpr (EPI == EPI_GELU) bcol = bias[col];
#pragma unroll
          for (int r = 0; r < 4; ++r) {
            const int lr = mm * 16 + (lhi << 2) + r;
            const float v = acc[m][n][r];
            bf16 o;
            if constexpr (EPI == EPI_DYT) {
              o = (bf16)(tanhf(a2v * (v + bcol)) * wcol + bvcol);
            } else if constexpr (EPI == EPI_GELU) {
              const float g = v + bcol;
              o = (bf16)(0.5f * g * (1.0f + erff(g * 0.70710678118654752f)));
            } else if constexpr (EPI == EPI_SCORES) {
              const int row = wrow0 + mp * 32 + lr;
              o = (bf16)__expf(v * scale - fabsf((float)(row - col)) - mv[r]);
            } else if constexpr (EPI == EPI_PV) {
              o = (bf16)(v * mv[r]);
            } else {
              o = (bf16)v;
            }
            st[lr * 72 + n * 16 + l15] = o;
          }
        }
      }
      wait_lgkm0();
      if constexpr (EPI == EPI_QKV) {
        if (ccol_base >= 2048) {
          // V third: write TRANSPOSED to Vt[b][d][t] at (bf16*)Cv + 2*bsC.
          const int d = (ccol_base - 2048) + lane;
          const int grow0 = wrow0 + mp * 32;
          const int bb = grow0 >> 11;
          const int tt = grow0 & 2047;
          bf16* VT = (bf16*)Cv + 2ull * (size_t)bsC +
                     (size_t)bb * 2097152ull + (size_t)d * 2048 + tt;
#pragma unroll
          for (int tq = 0; tq < 4; ++tq) {
            bf16x8 w;
#pragma unroll
            for (int j = 0; j < 8; ++j) w[j] = st[(tq * 8 + j) * 72 + lane];
            *(bf16x8*)&VT[tq * 8] = w;
          }
        } else {
          bf16* C = (bf16*)Cv + (size_t)(ccol_base >> 10) * bsC;
#pragma unroll
          for (int k = 0; k < 4; ++k) {
            const int lr = lane8r + 8 * k;
            const bf16x8 v = *(const bf16x8*)&st[lr * 72 + lane8c * 8];
            const int grow = wrow0 + mp * 32 + lr;
            *(bf16x8*)&C[(size_t)grow * 1024 + (ccol_base & 1023) + lane8c * 8] = v;
          }
        }
      } else {
#pragma unroll
        for (int k = 0; k < 4; ++k) {
          const int lr = lane8r + 8 * k;
          const bf16x8 v = *(const bf16x8*)&st[lr * 72 + lane8c * 8];
          const int grow = wrow0 + mp * 32 + lr;
          bf16* C = (bf16*)Cv + (size_t)bz * bsC;
          *(bf16x8*)&C[(size_t)grow * N + ccol_base + lane8c * 8] = v;
          if constexpr (EPI == EPI_SCORES) {
            float s = 0.f;
#pragma unroll
            for (int j = 0; j < 8; ++j) s += (float)v[j];
            s += __shfl_xor(s, 1);
            s += __shfl_xor(s, 2);
            s += __shfl_xor(s, 4);
            if (lane8c == 0)
              atomicAdd(const_cast<float*>(bv) + (size_t)bz * 2048 + grow, s);
          }
        }
      }
      wait_lgkm0();
    }
  }
}

// ---------------------------------------------------------------------------
// reductions
// ---------------------------------------------------------------------------
DEVI float wave_red_sum(float v) {
#pragma unroll
  for (int o = 32; o > 0; o >>= 1) v += __shfl_xor(v, o);
  return v;
}
DEVI float wave_red_max(float v) {
#pragma unroll
  for (int o = 32; o > 0; o >>= 1) v = fmaxf(v, __shfl_xor(v, o));
  return v;
}
DEVI float block_red_max(float v, float* sm) {
  v = wave_red_max(v);
  if ((threadIdx.x & 63) == 0) sm[threadIdx.x >> 6] = v;
  __syncthreads();
  v = fmaxf(fmaxf(sm[0], sm[1]), fmaxf(sm[2], sm[3]));
  __syncthreads();
  return v;
}
DEVI float block_red_sum(float v, float* sm) {
  v = wave_red_sum(v);
  if ((threadIdx.x & 63) == 0) sm[threadIdx.x >> 6] = v;
  __syncthreads();
  v = sm[0] + sm[1] + sm[2] + sm[3];
  __syncthreads();
  return v;
}

// diag shift: m[row] = (Q_row . K_row) * scale; also zeroes rowsum[row]
__global__ __launch_bounds__(256) void diag_k(const bf16* __restrict__ Q,
                                              const bf16* __restrict__ K,
                                              float* __restrict__ m,
                                              float* __restrict__ rowsum, float scale) {
  const int row = blockIdx.x * 4 + (threadIdx.x >> 6);
  const int lane = threadIdx.x & 63;
  const bf16* q = Q + (size_t)row * 1024 + lane * 16;
  const bf16* k = K + (size_t)row * 1024 + lane * 16;
  float s = 0.f;
#pragma unroll
  for (int j = 0; j < 2; ++j) {
    const bf16x8 qv = *(const bf16x8*)(q + j * 8);
    const bf16x8 kv = *(const bf16x8*)(k + j * 8);
#pragma unroll
    for (int e = 0; e < 8; ++e) s += (float)qv[e] * (float)kv[e];
  }
  s = wave_red_sum(s);
  if (lane == 0) { m[row] = s * scale; rowsum[row] = 0.f; }
}

// ---------------------------------------------------------------------------
// fused: xpe = x + pos_embed; prior = dyt3(xpe) (BF16); xn = dyt1(xpe) (bf16)
// ---------------------------------------------------------------------------
__global__ __launch_bounds__(256) void ew_pre(
    const float* __restrict__ x, const float* __restrict__ pe,
    const float* __restrict__ a1p, const float* __restrict__ w1, const float* __restrict__ b1,
    const float* __restrict__ a3p, const float* __restrict__ w3, const float* __restrict__ b3,
    bf16* __restrict__ prior, bf16* __restrict__ xn, int total4)
{
  const float a1 = a1p[0], a3 = a3p[0];
  for (int i = blockIdx.x * 256 + threadIdx.x; i < total4; i += gridDim.x * 256) {
    const int dq = i & 255;
    const float4 xv  = ((const float4*)x)[i];
    const float4 pv  = ((const float4*)pe)[dq];
    const float4 w1v = ((const float4*)w1)[dq];
    const float4 b1v = ((const float4*)b1)[dq];
    const float4 w3v = ((const float4*)w3)[dq];
    const float4 b3v = ((const float4*)b3)[dq];
    const float x0 = xv.x + pv.x, x1 = xv.y + pv.y, x2 = xv.z + pv.z, x3 = xv.w + pv.w;
    bf16x4 prv;
    prv[0] = (bf16)(tanhf(a3 * x0) * w3v.x + b3v.x);
    prv[1] = (bf16)(tanhf(a3 * x1) * w3v.y + b3v.y);
    prv[2] = (bf16)(tanhf(a3 * x2) * w3v.z + b3v.z);
    prv[3] = (bf16)(tanhf(a3 * x3) * w3v.w + b3v.w);
    ((bf16x4*)prior)[i] = prv;
    bf16x4 o;
    o[0] = (bf16)(tanhf(a1 * x0) * w1v.x + b1v.x);
    o[1] = (bf16)(tanhf(a1 * x1) * w1v.y + b1v.y);
    o[2] = (bf16)(tanhf(a1 * x2) * w1v.z + b1v.z);
    o[3] = (bf16)(tanhf(a1 * x3) * w1v.w + b1v.w);
    ((bf16x4*)xn)[i] = o;
  }
}

// fp32 -> bf16 weight conversion, 6 segments via blockIdx.y
__global__ __launch_bounds__(256) void conv_w(
    const float* __restrict__ s0, const float* __restrict__ s1, const float* __restrict__ s2,
    const float* __restrict__ s3, const float* __restrict__ s4, const float* __restrict__ s5,
    bf16* __restrict__ d0, bf16* __restrict__ d1, bf16* __restrict__ d2,
    bf16* __restrict__ d3, bf16* __restrict__ d4, bf16* __restrict__ d5,
    int n0, int n1, int n2, int n3, int n4, int n5)
{
  const float* s; bf16* d; int n;
  switch (blockIdx.y) {
    case 0: s = s0; d = d0; n = n0; break;
    case 1: s = s1; d = d1; n = n1; break;
    case 2: s = s2; d = d2; n = n2; break;
    case 3: s = s3; d = d3; n = n3; break;
    case 4: s = s4; d = d4; n = n4; break;
    default: s = s5; d = d5; n = n5; break;
  }
  const int nq = n >> 2;
  for (int i = blockIdx.x * 256 + threadIdx.x; i < nq; i += gridDim.x * 256) {
    const float4 v = ((const float4*)s)[i];
    bf16x4 o;
    o[0] = (bf16)v.x; o[1] = (bf16)v.y; o[2] = (bf16)v.z; o[3] = (bf16)v.w;
    ((bf16x4*)d)[i] = o;
  }
}

// per-row JS pieces -> per-row partials (prior is bf16)
__global__ __launch_bounds__(256) void loss_k(const bf16* __restrict__ prior,
                                              const float* __restrict__ post,
                                              float* __restrict__ partial) {
  __shared__ float sm[4];
  const size_t row = blockIdx.x;
  const int t = threadIdx.x;
  const bf16x4 prb = *(const bf16x4*)&prior[row * 1024 + t * 4];
  const float4 po = *(const float4*)&post[row * 1024 + t * 4];
  float4 pr;
  pr.x = (float)prb[0]; pr.y = (float)prb[1]; pr.z = (float)prb[2]; pr.w = (float)prb[3];
  float4 mm;
  mm.x = 0.5f * (pr.x + po.x); mm.y = 0.5f * (pr.y + po.y);
  mm.z = 0.5f * (pr.z + po.z); mm.w = 0.5f * (pr.w + po.w);
  const float mxp = block_red_max(fmaxf(fmaxf(pr.x, pr.y), fmaxf(pr.z, pr.w)), sm);
  const float mxo = block_red_max(fmaxf(fmaxf(po.x, po.y), fmaxf(po.z, po.w)), sm);
  const float mxm = block_red_max(fmaxf(fmaxf(mm.x, mm.y), fmaxf(mm.z, mm.w)), sm);
  float sp = expf(pr.x - mxp) + expf(pr.y - mxp) + expf(pr.z - mxp) + expf(pr.w - mxp);
  sp = block_red_sum(sp, sm);
  float so = expf(po.x - mxo) + expf(po.y - mxo) + expf(po.z - mxo) + expf(po.w - mxo);
  so = block_red_sum(so, sm);
  const float em0 = expf(mm.x - mxm), em1 = expf(mm.y - mxm), em2 = expf(mm.z - mxm), em3 = expf(mm.w - mxm);
  float smm = block_red_sum(em0 + em1 + em2 + em3, sm);
  const float invm = 1.0f / smm;
  float s1 = em0 * invm * (mm.x - pr.x) + em1 * invm * (mm.y - pr.y) +
             em2 * invm * (mm.z - pr.z) + em3 * invm * (mm.w - pr.w);
  float s2 = em0 * invm * (mm.x - po.x) + em1 * invm * (mm.y - po.y) +
             em2 * invm * (mm.z - po.z) + em3 * invm * (mm.w - po.w);
  s1 = block_red_sum(s1, sm);
  s2 = block_red_sum(s2, sm);
  if (t == 0) {
    const float logZp = mxp + logf(sp);
    const float logZo = mxo + logf(so);
    const float logZm = mxm + logf(smm);
    partial[row]        = s1 + (logZp - logZm);
    partial[8192 + row] = s2 + (logZo - logZm);
  }
}

__global__ __launch_bounds__(1024) void loss_fin(const float* __restrict__ partial,
                                                 float* __restrict__ out) {
  __shared__ float sm[32];
  const int t = threadIdx.x;
  float a = 0.f, b = 0.f;
  for (int i = t; i < 8192; i += 1024) {
    a += partial[i];
    b += partial[8192 + i];
  }
  float v = a + b;
#pragma unroll
  for (int o = 32; o > 0; o >>= 1) v += __shfl_xor(v, o);
  if ((t & 63) == 0) sm[t >> 6] = v;
  __syncthreads();
  if (t == 0) {
    float s = 0.f;
#pragma unroll
    for (int w = 0; w < 16; ++w) s += sm[w];
    out[0] = 0.125f * s;
  }
}

// ---------------------------------------------------------------------------
extern "C" void kernel_launch(void* const* d_in, const int* in_sizes, int n_in,
                              void* d_out, int out_size, void* d_ws, size_t ws_size,
                              hipStream_t stream) {
  const float* x  = (const float*)d_in[0];
  const float* pe = (const float*)d_in[1];
  const float* a1 = (const float*)d_in[2];
  const float* w1 = (const float*)d_in[3];
  const float* b1 = (const float*)d_in[4];
  const float* a2 = (const float*)d_in[5];
  const float* w2 = (const float*)d_in[6];
  const float* b2 = (const float*)d_in[7];
  const float* a3 = (const float*)d_in[8];
  const float* w3 = (const float*)d_in[9];
  const float* b3 = (const float*)d_in[10];
  const float* Wq = (const float*)d_in[11];
  const float* Wk = (const float*)d_in[12];
  const float* Wv = (const float*)d_in[13];
  const float* Wp = (const float*)d_in[14];
  const float* bp = (const float*)d_in[15];
  const float* We = (const float*)d_in[16];
  const float* be = (const float*)d_in[17];
  const float* Wc = (const float*)d_in[18];
  const float* bc = (const float*)d_in[19];
  float* out = (float*)d_out;

  char* ws = (char*)d_ws;
  bf16*  prior  = (bf16*)(ws + 0);               // 16.8 MB bf16
  bf16*  xn     = (bf16*)(ws + 33554432ull);     // reused: attn out
  bf16*  Qb     = (bf16*)(ws + 50331648ull);     // Q; K at +bsC; Vt at +2*bsC
  bf16*  Kb     = (bf16*)(ws + 67108864ull);
  bf16*  Vt     = (bf16*)(ws + 83886080ull);     // V TRANSPOSED [B][D][T]
  float* rowsum = (float*)(ws + 100663296ull);   // 32KB
  float* mvec   = (float*)(ws + 100728832ull);   // 32KB diag shift
  float* scores = (float*)(ws + 117440512ull);   // eb bf16 region, loss partials
  bf16*  Wqb    = (bf16*)(ws + 184549376ull);    // Wq/Wk/Wv contiguous
  bf16*  Wkb    = (bf16*)(ws + 186646528ull);
  bf16*  Wvb    = (bf16*)(ws + 188743680ull);
  bf16*  Wpb    = (bf16*)(ws + 190840832ull);
  bf16*  Web    = (bf16*)(ws + 192937984ull);
  bf16*  Wcb    = (bf16*)(ws + 201326592ull);
  bf16*  attno  = xn;
  bf16*  h2     = Qb;
  bf16*  eb     = (bf16*)scores;
  float* partial = (float*)(ws + 117440512ull);
  bf16*  probs  = (bf16*)d_out;  // unnormalized exp scores (bf16), banded

  static bool attr_done = false;
  if (!attr_done) {
    hipFuncSetAttribute((const void*)gemm2<EPI_QKV>,   hipFuncAttributeMaxDynamicSharedMemorySize, 73728);
    hipFuncSetAttribute((const void*)gemm2<EPI_SCORES>,hipFuncAttributeMaxDynamicSharedMemorySize, 73728);
    hipFuncSetAttribute((const void*)gemm2<EPI_PV>,    hipFuncAttributeMaxDynamicSharedMemorySize, 73728);
    hipFuncSetAttribute((const void*)gemm2<EPI_DYT>,   hipFuncAttributeMaxDynamicSharedMemorySize, 73728);
    hipFuncSetAttribute((const void*)gemm2<EPI_GELU>,  hipFuncAttributeMaxDynamicSharedMemorySize, 73728);
    hipFuncSetAttribute((const void*)gemm2<EPI_PRIOR>, hipFuncAttributeMaxDynamicSharedMemorySize, 73728);
    attr_done = true;
  }

  dim3 blk(256);
  dim3 gblk(512);
  constexpr unsigned SH = 73728;   // ring-3 * 24KB -> 2 blocks/CU

  conv_w<<<dim3(1024, 6), blk, 0, stream>>>(Wq, Wk, Wv, Wp, We, Wc,
                                            Wqb, Wkb, Wvb, Wpb, Web, Wcb,
                                            1048576, 1048576, 1048576, 1048576, 4194304, 4194304);
  ew_pre<<<2048, blk, 0, stream>>>(x, pe, a1, w1, b1, a3, w3, b3, prior, xn, 2097152);

  // fused QKV: [8192,3072] = xn @ [Wq;Wk;Wv]^T; V third written transposed
  gemm2<EPI_QKV><<<dim3(12, 64, 1), gblk, SH, stream>>>(xn, Wqb, Qb, 3072, 1024,
      0, 0, 8388608ll, nullptr, nullptr, nullptr, nullptr, nullptr, 0.f);

  // diag shift m[row] = (Q_row . K_row)/32 ; also zeroes rowsum
  diag_k<<<2048, blk, 0, stream>>>(Qb, Kb, mvec, rowsum, 0.03125f);

  // BANDED e[b,t,s] = exp((Q.K)/32 - |t-s| - m[t]) (bf16) + rowsum atomics.
  // bx'=0..1 -> col-blocks cb0(by)..cb1(by); off-band blocks are bf16-zero.
  gemm2<EPI_SCORES><<<dim3(2, 16, 4), gblk, SH, stream>>>(Qb, Kb, probs, 2048, 1024,
      2097152ll, 2097152ll, 4194304ll, nullptr, mvec, nullptr, rowsum, nullptr, 0.03125f);

  // BANDED out[b,t,d] = (e @ Vt) / rowsum[t]  (K-loop over written window)
  gemm2<EPI_PV><<<dim3(4, 16, 4), gblk, SH, stream>>>(probs, Vt, attno, 1024, 2048,
      4194304ll, 2097152ll, 2097152ll, nullptr, rowsum, nullptr, nullptr, nullptr, 0.f);

  // proj + dyt2
  gemm2<EPI_DYT><<<dim3(4, 64, 1), gblk, SH, stream>>>(attno, Wpb, h2, 1024, 1024,
      0, 0, 0, bp, a2, w2, b2, nullptr, 0.f);
  // expand + exact gelu
  gemm2<EPI_GELU><<<dim3(16, 64, 1), gblk, SH, stream>>>(h2, Web, eb, 4096, 1024,
      0, 0, 0, be, nullptr, nullptr, nullptr, nullptr, 0.f);
  // contract + bias + bf16 prior -> posterior (fp32)
  gemm2<EPI_PRIOR><<<dim3(4, 64, 1), gblk, SH, stream>>>(eb, Wcb, out, 1024, 4096,
      0, 0, 0, bc, nullptr, nullptr, nullptr, prior, 0.f);

  loss_k<<<8192, blk, 0, stream>>>(prior, out, partial);
  loss_fin<<<1, 1024, 0, stream>>>(partial, out + 8388608);
}